// Round 1
// baseline (651.971 us; speedup 1.0000x reference)
//
#include <hip/hip_runtime.h>
#include <math.h>

#define B_ 2
#define T_ 1024
#define S_ 1024
#define E_ 1024
#define H_ 16
#define D_ 64
#define SCALING_ 0.125f

// ---------------------------------------------------------------------------
// Mask dtype detection: key_padding_mask is jnp bool. Harness may hand it to
// us as int8 (1B), int32 (4B), or int64 (8B) per element. Detect on-device.
// mode: 0 = int32, 1 = int8, 2 = int64
// Detection: view first 2048 bytes as 512 u32 words (in-bounds for ALL
// hypotheses). If any word > 1 -> int8 (packed 0/1 bytes). Else buffer is
// >= 8KB; scan words 0..2047: if all odd-index words are 0 -> int64
// (high halves), else int32. ~10% ones makes misdetection probability ~0.
// ---------------------------------------------------------------------------
__global__ void mask_detect_kernel(const unsigned int* __restrict__ p,
                                   int* __restrict__ mode_out) {
    __shared__ int gt1_s, oddnz_s;
    if (threadIdx.x == 0) { gt1_s = 0; oddnz_s = 0; }
    __syncthreads();
    int gt1 = 0;
    for (int i = threadIdx.x; i < 512; i += 256)
        if (p[i] > 1u) gt1 = 1;
    if (gt1) atomicOr(&gt1_s, 1);
    __syncthreads();
    if (gt1_s == 0) {  // buffer is at least 8KB; safe to read 2048 words
        int oddnz = 0;
        for (int i = threadIdx.x; i < 2048; i += 256)
            if ((i & 1) && p[i] != 0u) oddnz = 1;
        if (oddnz) atomicOr(&oddnz_s, 1);
    }
    __syncthreads();
    if (threadIdx.x == 0)
        *mode_out = gt1_s ? 1 : (oddnz_s ? 0 : 2);
}

__global__ void mask_norm_kernel(const void* __restrict__ p,
                                 const int* __restrict__ mode_p,
                                 int* __restrict__ mout) {
    int i = blockIdx.x * 256 + threadIdx.x;  // 0..2047
    int mode = *mode_p;
    int v;
    if (mode == 1)      v = (int)((const unsigned char*)p)[i];
    else if (mode == 2) v = ((const int*)p)[2 * i];  // little-endian low word
    else                v = ((const int*)p)[i];
    mout[i] = v;
}

// ---------------------------------------------------------------------------
// GEMM: out[M,N] = alpha * (X[M,K] @ W[N,K]^T + bias[N])
// 64x64 tile / block (256 threads), BK=16, 4x4 microtile per thread.
// ---------------------------------------------------------------------------
template <int M, int N, int K>
__global__ __launch_bounds__(256) void gemm_xwt_kernel(
    const float* __restrict__ X, const float* __restrict__ W,
    const float* __restrict__ bias, float* __restrict__ out, float alpha) {
    __shared__ float As[16][64];  // [k][m]
    __shared__ float Bs[16][64];  // [k][n]
    const int tid = threadIdx.x;
    const int bn = blockIdx.x % (N / 64);
    const int bm = blockIdx.x / (N / 64);
    const int m0 = bm * 64, n0 = bn * 64;
    const int tm = (tid & 15) * 4;
    const int tn = (tid >> 4) * 4;
    const int lr = tid >> 2;         // load row within tile (0..63)
    const int lc = (tid & 3) * 4;    // load col within BK (0,4,8,12)

    float c[4][4] = {};
    for (int k0 = 0; k0 < K; k0 += 16) {
        float4 av = *(const float4*)&X[(size_t)(m0 + lr) * K + k0 + lc];
        float4 wv = *(const float4*)&W[(size_t)(n0 + lr) * K + k0 + lc];
        __syncthreads();  // previous iteration's reads complete
        As[lc + 0][lr] = av.x; As[lc + 1][lr] = av.y;
        As[lc + 2][lr] = av.z; As[lc + 3][lr] = av.w;
        Bs[lc + 0][lr] = wv.x; Bs[lc + 1][lr] = wv.y;
        Bs[lc + 2][lr] = wv.z; Bs[lc + 3][lr] = wv.w;
        __syncthreads();
#pragma unroll
        for (int kk = 0; kk < 16; kk++) {
            float4 a4 = *(const float4*)&As[kk][tm];
            float4 b4 = *(const float4*)&Bs[kk][tn];
            float a_[4] = {a4.x, a4.y, a4.z, a4.w};
            float b_[4] = {b4.x, b4.y, b4.z, b4.w};
#pragma unroll
            for (int i = 0; i < 4; i++)
#pragma unroll
                for (int j = 0; j < 4; j++)
                    c[i][j] = fmaf(a_[i], b_[j], c[i][j]);
        }
    }
    float4 bv = *(const float4*)&bias[n0 + tn];
    float b_[4] = {bv.x, bv.y, bv.z, bv.w};
#pragma unroll
    for (int i = 0; i < 4; i++) {
        float4 o4;
        o4.x = alpha * (c[i][0] + b_[0]);
        o4.y = alpha * (c[i][1] + b_[1]);
        o4.z = alpha * (c[i][2] + b_[2]);
        o4.w = alpha * (c[i][3] + b_[3]);
        *(float4*)&out[(size_t)(m0 + tm + i) * N + n0 + tn] = o4;
    }
}

// ---------------------------------------------------------------------------
// Flash attention (fp32). One block = one (b, h, 64-row T tile).
// Online softmax. mask -> -inf applied BEFORE bias add (matches reference).
// q is pre-scaled by SCALING_ (folded into Q projection).
// ---------------------------------------------------------------------------
__global__ __launch_bounds__(256) void flash_attn_kernel(
    const float* __restrict__ q, const float* __restrict__ k,
    const float* __restrict__ v, const float* __restrict__ bias,
    const int* __restrict__ mask, float* __restrict__ o) {
    __shared__ float Qt[64][64];  // [d][t]
    __shared__ float Kt[64][64];  // [d][s]
    __shared__ float Vs[64][64];  // [s][d]
    __shared__ float Pt[64][64];  // [s][t]
    __shared__ float rowscale[64];
    __shared__ float rowsum[64];

    const int tid = threadIdx.x;
    const int bh = blockIdx.x >> 4;  // 0..31
    const int tt = blockIdx.x & 15;
    const int b = bh >> 4;           // /H
    const int h = bh & 15;
    const int t0 = tt * 64;
    const int tm = (tid & 15) * 4;   // microtile rows (t)
    const int tn = (tid >> 4) * 4;   // microtile cols (s or d)
    const int lr = tid >> 2;         // load row
    const int lc4 = (tid & 3);       // load col quarter
    const int sr = tid >> 2;         // softmax row
    const int sj = tid & 3;          // softmax sub-index

    // Load Q tile transposed [d][t]
    {
        const float* qp = q + ((size_t)(b * T_) + t0 + lr) * E_ + h * 64;
#pragma unroll
        for (int u = 0; u < 4; u++) {
            int d0 = lc4 * 16 + u * 4;
            float4 qv = *(const float4*)&qp[d0];
            Qt[d0 + 0][lr] = qv.x; Qt[d0 + 1][lr] = qv.y;
            Qt[d0 + 2][lr] = qv.z; Qt[d0 + 3][lr] = qv.w;
        }
    }

    float m = -__builtin_inff(), l = 0.f;
    float acc[4][4] = {};
    const float* biasp = bias + ((size_t)bh * T_ + t0) * S_;

    for (int s0 = 0; s0 < S_; s0 += 64) {
        __syncthreads();  // prev PV reads of Kt/Vs/Pt complete
        const float* kp = k + ((size_t)(b * S_) + s0 + lr) * E_ + h * 64;
        const float* vp = v + ((size_t)(b * S_) + s0 + lr) * E_ + h * 64;
#pragma unroll
        for (int u = 0; u < 4; u++) {
            int d0 = lc4 * 16 + u * 4;
            float4 kv = *(const float4*)&kp[d0];
            Kt[d0 + 0][lr] = kv.x; Kt[d0 + 1][lr] = kv.y;
            Kt[d0 + 2][lr] = kv.z; Kt[d0 + 3][lr] = kv.w;
            float4 vv = *(const float4*)&vp[d0];
            *(float4*)&Vs[lr][d0] = vv;
        }
        __syncthreads();

        // Scores: sc[t][s] = sum_d Qt[d][t] * Kt[d][s]
        float sc[4][4] = {};
#pragma unroll 8
        for (int d = 0; d < 64; d++) {
            float4 qa = *(const float4*)&Qt[d][tm];
            float4 kb = *(const float4*)&Kt[d][tn];
            float a_[4] = {qa.x, qa.y, qa.z, qa.w};
            float b_[4] = {kb.x, kb.y, kb.z, kb.w};
#pragma unroll
            for (int i = 0; i < 4; i++)
#pragma unroll
                for (int j = 0; j < 4; j++)
                    sc[i][j] = fmaf(a_[i], b_[j], sc[i][j]);
        }
        // mask -> -inf, then += bias; write to Pt[s][t]
        int mk[4];
#pragma unroll
        for (int j = 0; j < 4; j++) mk[j] = mask[b * S_ + s0 + tn + j];
#pragma unroll
        for (int i = 0; i < 4; i++) {
            float4 bv4 = *(const float4*)&biasp[(size_t)(tm + i) * S_ + s0 + tn];
            float b_[4] = {bv4.x, bv4.y, bv4.z, bv4.w};
#pragma unroll
            for (int j = 0; j < 4; j++) {
                float val = mk[j] ? -__builtin_inff() : sc[i][j];
                val += b_[j];
                Pt[tn + j][tm + i] = val;
            }
        }
        __syncthreads();

        // Online softmax: row sr handled by 4 threads (sj covers 16 s each)
        float s16[16];
        float tmax = -__builtin_inff();
#pragma unroll
        for (int i = 0; i < 16; i++) {
            s16[i] = Pt[sj * 16 + i][sr];
            tmax = fmaxf(tmax, s16[i]);
        }
        tmax = fmaxf(tmax, __shfl_xor(tmax, 1, 64));
        tmax = fmaxf(tmax, __shfl_xor(tmax, 2, 64));
        float mnew = fmaxf(m, tmax);
        float escale, psum = 0.f;
        if (mnew > -__builtin_inff()) {
            escale = __expf(m - mnew);  // m=-inf first tile -> 0
#pragma unroll
            for (int i = 0; i < 16; i++) {
                s16[i] = __expf(s16[i] - mnew);
                psum += s16[i];
            }
        } else {  // fully-masked rows so far
            escale = 1.f;
#pragma unroll
            for (int i = 0; i < 16; i++) s16[i] = 0.f;
        }
#pragma unroll
        for (int i = 0; i < 16; i++) Pt[sj * 16 + i][sr] = s16[i];
        psum += __shfl_xor(psum, 1, 64);
        psum += __shfl_xor(psum, 2, 64);
        l = l * escale + psum;
        m = mnew;
        if (sj == 0) rowscale[sr] = escale;
        __syncthreads();

        // PV: acc[t][d] = acc*escale(row) + sum_s Pt[s][t] * Vs[s][d]
        float4 rsv = *(const float4*)&rowscale[tm];
        float rs_[4] = {rsv.x, rsv.y, rsv.z, rsv.w};
#pragma unroll
        for (int i = 0; i < 4; i++)
#pragma unroll
            for (int j = 0; j < 4; j++) acc[i][j] *= rs_[i];
#pragma unroll 8
        for (int s = 0; s < 64; s++) {
            float4 pa = *(const float4*)&Pt[s][tm];
            float4 vb = *(const float4*)&Vs[s][tn];
            float a_[4] = {pa.x, pa.y, pa.z, pa.w};
            float b_[4] = {vb.x, vb.y, vb.z, vb.w};
#pragma unroll
            for (int i = 0; i < 4; i++)
#pragma unroll
                for (int j = 0; j < 4; j++)
                    acc[i][j] = fmaf(a_[i], b_[j], acc[i][j]);
        }
    }

    if (sj == 0) rowsum[sr] = l;
    __syncthreads();
    float4 lv = *(const float4*)&rowsum[tm];
    float l_[4] = {lv.x, lv.y, lv.z, lv.w};
    float* op = o + ((size_t)(b * T_) + t0) * E_ + h * 64;
#pragma unroll
    for (int i = 0; i < 4; i++) {
        float inv = 1.f / l_[i];
        float4 o4;
        o4.x = acc[i][0] * inv; o4.y = acc[i][1] * inv;
        o4.z = acc[i][2] * inv; o4.w = acc[i][3] * inv;
        *(float4*)&op[(size_t)(tm + i) * E_ + tn] = o4;
    }
}

// ---------------------------------------------------------------------------
extern "C" void kernel_launch(void* const* d_in, const int* in_sizes, int n_in,
                              void* d_out, int out_size, void* d_ws,
                              size_t ws_size, hipStream_t stream) {
    const float* query = (const float*)d_in[0];
    const float* key   = (const float*)d_in[1];
    const float* value = (const float*)d_in[2];
    const void*  kpm   = d_in[3];
    const float* attn_bias = (const float*)d_in[4];
    const float* Wq = (const float*)d_in[5];
    const float* bq = (const float*)d_in[6];
    const float* Wk = (const float*)d_in[7];
    const float* bk = (const float*)d_in[8];
    const float* Wv = (const float*)d_in[9];
    const float* bv = (const float*)d_in[10];
    const float* Wo = (const float*)d_in[11];
    const float* bo = (const float*)d_in[12];
    float* out = (float*)d_out;

    char* ws = (char*)d_ws;
    const size_t MB = 1024 * 1024;
    float* qbuf = (float*)(ws + 0 * MB);       // 8 MB  [B*T, E]
    float* kbuf = (float*)(ws + 8 * MB);       // 8 MB  [B*S, E]
    float* vbuf = (float*)(ws + 16 * MB);      // 8 MB  [B*S, E]
    float* obuf = (float*)(ws + 24 * MB);      // 8 MB  [B*T, E]
    int* masknorm = (int*)(ws + 32 * MB);      // 2048 ints
    int* mode = masknorm + 2048;

    mask_detect_kernel<<<1, 256, 0, stream>>>((const unsigned int*)kpm, mode);
    mask_norm_kernel<<<8, 256, 0, stream>>>(kpm, mode, masknorm);

    // Projections (SCALING folded into Q)
    gemm_xwt_kernel<2048, 1024, 1024><<<512, 256, 0, stream>>>(
        query, Wq, bq, qbuf, SCALING_);
    gemm_xwt_kernel<2048, 1024, 1024><<<512, 256, 0, stream>>>(
        key, Wk, bk, kbuf, 1.f);
    gemm_xwt_kernel<2048, 1024, 1024><<<512, 256, 0, stream>>>(
        value, Wv, bv, vbuf, 1.f);

    // Attention
    flash_attn_kernel<<<512, 256, 0, stream>>>(qbuf, kbuf, vbuf, attn_bias,
                                               masknorm, obuf);

    // Output projection
    gemm_xwt_kernel<2048, 1024, 1024><<<512, 256, 0, stream>>>(
        obuf, Wo, bo, out, 1.f);
}

// Round 2
// 443.104 us; speedup vs baseline: 1.4714x; 1.4714x over previous
//
#include <hip/hip_runtime.h>
#include <math.h>
#include <stdint.h>

#define B_ 2
#define T_ 1024
#define S_ 1024
#define E_ 1024
#define H_ 16
#define SCALING_ 0.125f

typedef short bf16x8 __attribute__((ext_vector_type(8)));   // 8 bf16 (4 VGPR) MFMA frag
typedef float f32x4 __attribute__((ext_vector_type(4)));    // MFMA acc frag
typedef unsigned short us8 __attribute__((ext_vector_type(8)));

__device__ __forceinline__ unsigned short f2bf(float x) {  // RNE fp32->bf16
    unsigned int u = __float_as_uint(x);
    return (unsigned short)((u + 0x7fffu + ((u >> 16) & 1u)) >> 16);
}
__device__ __forceinline__ float bf2f(unsigned short h) {
    return __uint_as_float(((unsigned int)h) << 16);
}
__device__ __forceinline__ void split_bf(float x, unsigned short& hh, unsigned short& ll) {
    hh = f2bf(x);
    ll = f2bf(x - bf2f(hh));
}
// async global->LDS, 16B per lane. LDS dest must be linear in lane order.
__device__ __forceinline__ void gl_lds16(const void* g, void* l) {
    __builtin_amdgcn_global_load_lds(
        (const __attribute__((address_space(1))) unsigned int*)g,
        (__attribute__((address_space(3))) unsigned int*)l, 16, 0, 0);
}

// ---------------------------------------------------------------------------
// Mask dtype detection + normalization (validated in round 1).
// ---------------------------------------------------------------------------
__global__ void mask_detect_kernel(const unsigned int* __restrict__ p,
                                   int* __restrict__ mode_out) {
    __shared__ int gt1_s, oddnz_s;
    if (threadIdx.x == 0) { gt1_s = 0; oddnz_s = 0; }
    __syncthreads();
    int gt1 = 0;
    for (int i = threadIdx.x; i < 512; i += 256)
        if (p[i] > 1u) gt1 = 1;
    if (gt1) atomicOr(&gt1_s, 1);
    __syncthreads();
    if (gt1_s == 0) {
        int oddnz = 0;
        for (int i = threadIdx.x; i < 2048; i += 256)
            if ((i & 1) && p[i] != 0u) oddnz = 1;
        if (oddnz) atomicOr(&oddnz_s, 1);
    }
    __syncthreads();
    if (threadIdx.x == 0)
        *mode_out = gt1_s ? 1 : (oddnz_s ? 0 : 2);
}

__global__ void mask_norm_kernel(const void* __restrict__ p,
                                 const int* __restrict__ mode_p,
                                 int* __restrict__ mout) {
    int i = blockIdx.x * 256 + threadIdx.x;  // 0..2047
    int mode = *mode_p;
    int v;
    if (mode == 1)      v = (int)((const unsigned char*)p)[i];
    else if (mode == 2) v = ((const int*)p)[2 * i];
    else                v = ((const int*)p)[i];
    mout[i] = v;
}

// ---------------------------------------------------------------------------
// fp32 -> (bf16 hi, bf16 lo) planar split. 8 elems/thread.
// ---------------------------------------------------------------------------
__global__ __launch_bounds__(256) void conv_split_kernel(
    const float* __restrict__ src, unsigned short* __restrict__ dh,
    unsigned short* __restrict__ dl, int n) {
    int i = (blockIdx.x * 256 + threadIdx.x) * 8;
    if (i >= n) return;
    float4 a = *(const float4*)&src[i];
    float4 b = *(const float4*)&src[i + 4];
    float v[8] = {a.x, a.y, a.z, a.w, b.x, b.y, b.z, b.w};
    us8 vh, vl;
#pragma unroll
    for (int j = 0; j < 8; j++) {
        unsigned short hh, ll;
        split_bf(v[j], hh, ll);
        vh[j] = hh; vl[j] = ll;
    }
    *(us8*)&dh[i] = vh;
    *(us8*)&dl[i] = vl;
}

// ---------------------------------------------------------------------------
// Split-bf16 GEMM: out[M,N] = alpha * (A[M,K] . B[N,K]^T + bias)
// 128x64 tile, BK=32, 4 waves (2x2), 16x16x32 MFMA, 3-term split product.
// A_F32/B_F32: operand is raw fp32 (reg-stage + split into LDS);
// else operand is pre-split bf16 hi/lo (global_load_lds, source pre-swizzled).
// LDS chunk swizzle (rows of 64B = 4 chunks): chunk' = chunk ^ ((row>>1)&3).
// ---------------------------------------------------------------------------
template <int M, int N, int K, int A_F32, int B_F32, int ROWBIAS, int SPLITOUT>
__global__ __launch_bounds__(256) void gemm_kernel(
    const void* __restrict__ Aph, const void* __restrict__ Apl,
    const void* __restrict__ Bph, const void* __restrict__ Bpl,
    const float* __restrict__ bias,
    unsigned short* __restrict__ outh, unsigned short* __restrict__ outl,
    float* __restrict__ outf, float alpha) {
    __shared__ __align__(16) unsigned short Ash[128 * 32], Asl[128 * 32];
    __shared__ __align__(16) unsigned short Bsh[64 * 32], Bsl[64 * 32];

    const int tid = threadIdx.x;
    const int lane = tid & 63;
    const int wave = tid >> 6;
    const int wm = wave >> 1, wn = wave & 1;
    const int bn = blockIdx.x % (N / 64);
    const int bm = blockIdx.x / (N / 64);
    const int m0 = bm * 128, n0 = bn * 64;
    const int srow = tid >> 2;   // staging row (0..63, +64 on pass 1)
    const int soct = tid & 3;    // staging k-octet

    f32x4 acc[4][2];
#pragma unroll
    for (int i = 0; i < 4; i++)
#pragma unroll
        for (int j = 0; j < 2; j++) acc[i][j] = (f32x4){0.f, 0.f, 0.f, 0.f};

    for (int k0 = 0; k0 < K; k0 += 32) {
        __syncthreads();  // previous iteration's frag reads complete
        // ---- stage A (128x32, 2 passes) ----
        if (A_F32) {
            const float* A = (const float*)Aph;
#pragma unroll
            for (int p = 0; p < 2; p++) {
                int row = p * 64 + srow;
                const float* s = &A[(size_t)(m0 + row) * K + k0 + soct * 8];
                float4 x = *(const float4*)s;
                float4 y = *(const float4*)(s + 4);
                float v[8] = {x.x, x.y, x.z, x.w, y.x, y.y, y.z, y.w};
                us8 vh, vl;
#pragma unroll
                for (int j = 0; j < 8; j++) {
                    unsigned short hh, ll;
                    split_bf(v[j], hh, ll);
                    vh[j] = hh; vl[j] = ll;
                }
                int oct2 = soct ^ ((row >> 1) & 3);
                *(us8*)&Ash[row * 32 + oct2 * 8] = vh;
                *(us8*)&Asl[row * 32 + oct2 * 8] = vl;
            }
        } else {
            const unsigned short* Ah = (const unsigned short*)Aph;
            const unsigned short* Al = (const unsigned short*)Apl;
#pragma unroll
            for (int p = 0; p < 2; p++) {
                int row = p * 64 + srow;
                int oct2 = soct ^ ((row >> 1) & 3);  // pre-swizzled source
                size_t g = (size_t)(m0 + row) * K + k0 + oct2 * 8;
                gl_lds16(&Ah[g], &Ash[row * 32 + soct * 8]);
                gl_lds16(&Al[g], &Asl[row * 32 + soct * 8]);
            }
        }
        // ---- stage B (64x32, 1 pass) ----
        if (B_F32) {
            const float* Bv = (const float*)Bph;
            int row = srow;
            const float* s = &Bv[(size_t)(n0 + row) * K + k0 + soct * 8];
            float4 x = *(const float4*)s;
            float4 y = *(const float4*)(s + 4);
            float v[8] = {x.x, x.y, x.z, x.w, y.x, y.y, y.z, y.w};
            us8 vh, vl;
#pragma unroll
            for (int j = 0; j < 8; j++) {
                unsigned short hh, ll;
                split_bf(v[j], hh, ll);
                vh[j] = hh; vl[j] = ll;
            }
            int oct2 = soct ^ ((row >> 1) & 3);
            *(us8*)&Bsh[row * 32 + oct2 * 8] = vh;
            *(us8*)&Bsl[row * 32 + oct2 * 8] = vl;
        } else {
            const unsigned short* Bh = (const unsigned short*)Bph;
            const unsigned short* Bl = (const unsigned short*)Bpl;
            int row = srow;
            int oct2 = soct ^ ((row >> 1) & 3);
            size_t g = (size_t)(n0 + row) * K + k0 + oct2 * 8;
            gl_lds16(&Bh[g], &Bsh[row * 32 + soct * 8]);
            gl_lds16(&Bl[g], &Bsl[row * 32 + soct * 8]);
        }
        asm volatile("s_waitcnt vmcnt(0)" ::: "memory");
        __syncthreads();

        // ---- compute: 24 MFMA / 12 ds_read_b128 per wave ----
        bf16x8 bh_[2], bl_[2];
#pragma unroll
        for (int nj = 0; nj < 2; nj++) {
            int rowB = wn * 32 + nj * 16 + (lane & 15);
            int ch = ((lane >> 4) ^ ((rowB >> 1) & 3));
            bh_[nj] = *(const bf16x8*)&Bsh[rowB * 32 + ch * 8];
            bl_[nj] = *(const bf16x8*)&Bsl[rowB * 32 + ch * 8];
        }
#pragma unroll
        for (int mi = 0; mi < 4; mi++) {
            int rowA = wm * 64 + mi * 16 + (lane & 15);
            int ch = ((lane >> 4) ^ ((rowA >> 1) & 3));
            bf16x8 afh = *(const bf16x8*)&Ash[rowA * 32 + ch * 8];
            bf16x8 afl = *(const bf16x8*)&Asl[rowA * 32 + ch * 8];
#pragma unroll
            for (int nj = 0; nj < 2; nj++) {
                acc[mi][nj] = __builtin_amdgcn_mfma_f32_16x16x32_bf16(afh, bh_[nj], acc[mi][nj], 0, 0, 0);
                acc[mi][nj] = __builtin_amdgcn_mfma_f32_16x16x32_bf16(afl, bh_[nj], acc[mi][nj], 0, 0, 0);
                acc[mi][nj] = __builtin_amdgcn_mfma_f32_16x16x32_bf16(afh, bl_[nj], acc[mi][nj], 0, 0, 0);
            }
        }
    }

    // ---- epilogue: bias, alpha, (split-)store ----
    float bcol[2];
    if (!ROWBIAS) {
#pragma unroll
        for (int nj = 0; nj < 2; nj++)
            bcol[nj] = bias[n0 + wn * 32 + nj * 16 + (lane & 15)];
    }
#pragma unroll
    for (int mi = 0; mi < 4; mi++) {
#pragma unroll
        for (int r = 0; r < 4; r++) {
            int row = m0 + wm * 64 + mi * 16 + (lane >> 4) * 4 + r;
            float brow = ROWBIAS ? bias[row] : 0.f;
#pragma unroll
            for (int nj = 0; nj < 2; nj++) {
                int col = n0 + wn * 32 + nj * 16 + (lane & 15);
                float v = alpha * (acc[mi][nj][r] + (ROWBIAS ? brow : bcol[nj]));
                if (SPLITOUT) {
                    unsigned short hh, ll;
                    split_bf(v, hh, ll);
                    outh[(size_t)row * N + col] = hh;
                    outl[(size_t)row * N + col] = ll;
                } else {
                    outf[(size_t)row * N + col] = v;
                }
            }
        }
    }
}

// ---------------------------------------------------------------------------
// Flash attention, split-bf16 MFMA. Block = (b, h, 64 t-rows); 4 waves x 16 t.
// q pre-scaled. V supplied TRANSPOSED ([E][B*S]) so staging is linear.
// Softmax state fully in registers (shuffle-reduce over 16-lane col groups).
// K/Q/Vt LDS: 128B rows, chunk' = chunk ^ (row&7).
// P LDS (per wave, [16t][64s]): chunk' = chunk ^ f(t), f(t)=((t>>2)&3)<<1|(t&1)
//   -> conflict-free scattered b16 writes AND 2-way b128 reads.
// ---------------------------------------------------------------------------
__global__ __launch_bounds__(256) void flash_kernel(
    const unsigned short* __restrict__ qh, const unsigned short* __restrict__ ql,
    const unsigned short* __restrict__ kh, const unsigned short* __restrict__ kl,
    const unsigned short* __restrict__ vth, const unsigned short* __restrict__ vtl,
    const float* __restrict__ bias, const int* __restrict__ mask,
    unsigned short* __restrict__ oh, unsigned short* __restrict__ ol) {
    __shared__ __align__(16) unsigned short Ksh[64 * 64], Ksl[64 * 64];
    __shared__ __align__(16) unsigned short Vsh[64 * 64], Vsl[64 * 64];
    __shared__ __align__(16) unsigned short Ph[4][16 * 64], Pl[4][16 * 64];

    const int tid = threadIdx.x;
    const int lane = tid & 63;
    const int wave = tid >> 6;
    const int bh = blockIdx.x >> 4;
    const int tt = blockIdx.x & 15;
    const int b = bh >> 4, h = bh & 15;
    const int t0 = tt * 64;
    const int srow = tid >> 3;  // staging row 0..31 (+32 pass 1)
    const int soct = tid & 7;   // staging d/s octet

    // ---- stage Q (into K buffers), hoist frags ----
#pragma unroll
    for (int p = 0; p < 2; p++) {
        int row = p * 32 + srow;
        int oct2 = soct ^ (row & 7);
        size_t g = (size_t)(b * T_ + t0 + row) * E_ + h * 64 + oct2 * 8;
        gl_lds16(&qh[g], &Ksh[row * 64 + soct * 8]);
        gl_lds16(&ql[g], &Ksl[row * 64 + soct * 8]);
    }
    asm volatile("s_waitcnt vmcnt(0)" ::: "memory");
    __syncthreads();
    bf16x8 qfh[2], qfl[2];
    {
        int row = wave * 16 + (lane & 15);
#pragma unroll
        for (int kk = 0; kk < 2; kk++) {
            int ch = (kk * 4 + (lane >> 4)) ^ (row & 7);
            qfh[kk] = *(const bf16x8*)&Ksh[row * 64 + ch * 8];
            qfl[kk] = *(const bf16x8*)&Ksl[row * 64 + ch * 8];
        }
    }
    __syncthreads();  // Q frag reads done before K staging overwrites

    float mrow[4] = {-INFINITY, -INFINITY, -INFINITY, -INFINITY};
    float lrow[4] = {0.f, 0.f, 0.f, 0.f};
    f32x4 oacc[4];
#pragma unroll
    for (int dj = 0; dj < 4; dj++) oacc[dj] = (f32x4){0.f, 0.f, 0.f, 0.f};

    const size_t bias0 = ((size_t)bh * T_ + t0 + wave * 16) * S_;

    for (int s0i = 0; s0i < 16; s0i++) {
        const int s0 = s0i * 64;
        __syncthreads();  // prev iter's K/V reads complete
#pragma unroll
        for (int p = 0; p < 2; p++) {
            int row = p * 32 + srow;
            int oct2 = soct ^ (row & 7);
            size_t gk = (size_t)(b * S_ + s0 + row) * E_ + h * 64 + oct2 * 8;
            gl_lds16(&kh[gk], &Ksh[row * 64 + soct * 8]);
            gl_lds16(&kl[gk], &Ksl[row * 64 + soct * 8]);
            size_t gv = (size_t)(h * 64 + row) * (B_ * S_) + b * S_ + s0 + oct2 * 8;
            gl_lds16(&vth[gv], &Vsh[row * 64 + soct * 8]);
            gl_lds16(&vtl[gv], &Vsl[row * 64 + soct * 8]);
        }
        // bias + mask loads overlap the staging in flight
        float bv[4][4];
        int mk[4];
#pragma unroll
        for (int nj = 0; nj < 4; nj++) {
            int s = s0 + nj * 16 + (lane & 15);
            mk[nj] = mask[b * S_ + s];
#pragma unroll
            for (int r = 0; r < 4; r++)
                bv[nj][r] = bias[bias0 + (size_t)((lane >> 4) * 4 + r) * S_ + s];
        }
        asm volatile("s_waitcnt vmcnt(0)" ::: "memory");
        __syncthreads();

        // ---- QK^T (split 3-term) ----
        f32x4 sc[4];
#pragma unroll
        for (int nj = 0; nj < 4; nj++) sc[nj] = (f32x4){0.f, 0.f, 0.f, 0.f};
#pragma unroll
        for (int kk = 0; kk < 2; kk++) {
#pragma unroll
            for (int nj = 0; nj < 4; nj++) {
                int row = nj * 16 + (lane & 15);
                int ch = (kk * 4 + (lane >> 4)) ^ (row & 7);
                bf16x8 kfh = *(const bf16x8*)&Ksh[row * 64 + ch * 8];
                bf16x8 kfl = *(const bf16x8*)&Ksl[row * 64 + ch * 8];
                sc[nj] = __builtin_amdgcn_mfma_f32_16x16x32_bf16(qfh[kk], kfh, sc[nj], 0, 0, 0);
                sc[nj] = __builtin_amdgcn_mfma_f32_16x16x32_bf16(qfl[kk], kfh, sc[nj], 0, 0, 0);
                sc[nj] = __builtin_amdgcn_mfma_f32_16x16x32_bf16(qfh[kk], kfl, sc[nj], 0, 0, 0);
            }
        }
        // mask -> -inf (BEFORE bias add, matches reference), then + bias
#pragma unroll
        for (int nj = 0; nj < 4; nj++)
#pragma unroll
            for (int r = 0; r < 4; r++) {
                float v = mk[nj] ? -INFINITY : sc[nj][r];
                sc[nj][r] = v + bv[nj][r];
            }

        // ---- online softmax (per r = t-row), all in registers ----
        unsigned short phv[4][4], plv[4][4];
#pragma unroll
        for (int r = 0; r < 4; r++) {
            float mx = fmaxf(fmaxf(sc[0][r], sc[1][r]), fmaxf(sc[2][r], sc[3][r]));
            mx = fmaxf(mx, __shfl_xor(mx, 1));
            mx = fmaxf(mx, __shfl_xor(mx, 2));
            mx = fmaxf(mx, __shfl_xor(mx, 4));
            mx = fmaxf(mx, __shfl_xor(mx, 8));
            float mnew = fmaxf(mrow[r], mx);
            float esc = __expf(mrow[r] - mnew);  // first tile: exp(-inf)=0
            float ps = 0.f;
#pragma unroll
            for (int nj = 0; nj < 4; nj++) {
                float p = __expf(sc[nj][r] - mnew);  // masked: exp(-inf)=0
                ps += p;
                split_bf(p, phv[nj][r], plv[nj][r]);
            }
            ps += __shfl_xor(ps, 1);
            ps += __shfl_xor(ps, 2);
            ps += __shfl_xor(ps, 4);
            ps += __shfl_xor(ps, 8);
            lrow[r] = lrow[r] * esc + ps;
            mrow[r] = mnew;
#pragma unroll
            for (int dj = 0; dj < 4; dj++) oacc[dj][r] *= esc;
        }

        // ---- write P (hi/lo) to per-wave swizzled LDS ----
#pragma unroll
        for (int r = 0; r < 4; r++) {
            int t = (lane >> 4) * 4 + r;
            int f = (((t >> 2) & 3) << 1) | (t & 1);
#pragma unroll
            for (int nj = 0; nj < 4; nj++) {
                int s = nj * 16 + (lane & 15);
                int idx = t * 64 + (((s >> 3) ^ f) * 8) + (s & 7);
                Ph[wave][idx] = phv[nj][r];
                Pl[wave][idx] = plv[nj][r];
            }
        }
        // ---- PV (split 3-term); same-wave P RAW handled by compiler lgkmcnt
        bf16x8 pah[2], pal[2];
        {
            int t = lane & 15;
            int f = (((t >> 2) & 3) << 1) | (t & 1);
#pragma unroll
            for (int kk = 0; kk < 2; kk++) {
                int ch = (kk * 4 + (lane >> 4)) ^ f;
                pah[kk] = *(const bf16x8*)&Ph[wave][t * 64 + ch * 8];
                pal[kk] = *(const bf16x8*)&Pl[wave][t * 64 + ch * 8];
            }
        }
#pragma unroll
        for (int dj = 0; dj < 4; dj++) {
            int row = dj * 16 + (lane & 15);
#pragma unroll
            for (int kk = 0; kk < 2; kk++) {
                int ch = (kk * 4 + (lane >> 4)) ^ (row & 7);
                bf16x8 vfh = *(const bf16x8*)&Vsh[row * 64 + ch * 8];
                bf16x8 vfl = *(const bf16x8*)&Vsl[row * 64 + ch * 8];
                oacc[dj] = __builtin_amdgcn_mfma_f32_16x16x32_bf16(pah[kk], vfh, oacc[dj], 0, 0, 0);
                oacc[dj] = __builtin_amdgcn_mfma_f32_16x16x32_bf16(pal[kk], vfh, oacc[dj], 0, 0, 0);
                oacc[dj] = __builtin_amdgcn_mfma_f32_16x16x32_bf16(pah[kk], vfl, oacc[dj], 0, 0, 0);
            }
        }
    }

    // ---- epilogue: O = acc / l, split-store to obuf ----
#pragma unroll
    for (int r = 0; r < 4; r++) {
        float inv = 1.f / lrow[r];
        int t = t0 + wave * 16 + (lane >> 4) * 4 + r;
#pragma unroll
        for (int dj = 0; dj < 4; dj++) {
            float v = oacc[dj][r] * inv;
            unsigned short hh, ll;
            split_bf(v, hh, ll);
            size_t g = (size_t)(b * T_ + t) * E_ + h * 64 + dj * 16 + (lane & 15);
            oh[g] = hh;
            ol[g] = ll;
        }
    }
}

// ---------------------------------------------------------------------------
extern "C" void kernel_launch(void* const* d_in, const int* in_sizes, int n_in,
                              void* d_out, int out_size, void* d_ws,
                              size_t ws_size, hipStream_t stream) {
    const float* query = (const float*)d_in[0];
    const float* key   = (const float*)d_in[1];
    const float* value = (const float*)d_in[2];
    const void*  kpm   = d_in[3];
    const float* attn_bias = (const float*)d_in[4];
    const float* Wq = (const float*)d_in[5];
    const float* bq = (const float*)d_in[6];
    const float* Wk = (const float*)d_in[7];
    const float* bk = (const float*)d_in[8];
    const float* Wv = (const float*)d_in[9];
    const float* bv = (const float*)d_in[10];
    const float* Wo = (const float*)d_in[11];
    const float* bo = (const float*)d_in[12];
    float* out = (float*)d_out;

    char* ws = (char*)d_ws;
    const size_t MB = 1024 * 1024;
    // weight splits (2MB each plane)
    unsigned short* Wqh = (unsigned short*)(ws + 0 * MB);
    unsigned short* Wql = (unsigned short*)(ws + 2 * MB);
    unsigned short* Wkh = (unsigned short*)(ws + 4 * MB);
    unsigned short* Wkl = (unsigned short*)(ws + 6 * MB);
    unsigned short* Wvh = (unsigned short*)(ws + 8 * MB);
    unsigned short* Wvl = (unsigned short*)(ws + 10 * MB);
    unsigned short* Woh = (unsigned short*)(ws + 12 * MB);
    unsigned short* Wol = (unsigned short*)(ws + 14 * MB);
    // activation splits (4MB each plane)
    unsigned short* qh = (unsigned short*)(ws + 16 * MB);
    unsigned short* ql = (unsigned short*)(ws + 20 * MB);
    unsigned short* kh = (unsigned short*)(ws + 24 * MB);
    unsigned short* kl = (unsigned short*)(ws + 28 * MB);
    unsigned short* vth = (unsigned short*)(ws + 32 * MB);  // V^T [E][B*S]
    unsigned short* vtl = (unsigned short*)(ws + 36 * MB);
    // flash output overlays Wq/Wk region (dead by then)
    unsigned short* oh = (unsigned short*)(ws + 0 * MB);
    unsigned short* ol = (unsigned short*)(ws + 4 * MB);
    int* masknorm = (int*)(ws + 40 * MB);
    int* mode = masknorm + 2048;

    // weight fp32 -> hi/lo bf16 planes
    conv_split_kernel<<<512, 256, 0, stream>>>(Wq, Wqh, Wql, E_ * E_);
    conv_split_kernel<<<512, 256, 0, stream>>>(Wk, Wkh, Wkl, E_ * E_);
    conv_split_kernel<<<512, 256, 0, stream>>>(Wv, Wvh, Wvl, E_ * E_);
    conv_split_kernel<<<512, 256, 0, stream>>>(Wo, Woh, Wol, E_ * E_);
    mask_detect_kernel<<<1, 256, 0, stream>>>((const unsigned int*)kpm, mode);
    mask_norm_kernel<<<8, 256, 0, stream>>>(kpm, mode, masknorm);

    // q = (query Wq^T + bq) * SCALING   [2048,1024]
    gemm_kernel<2048, 1024, 1024, 1, 0, 0, 1><<<256, 256, 0, stream>>>(
        query, nullptr, Wqh, Wql, bq, qh, ql, nullptr, SCALING_);
    // k = key Wk^T + bk                 [2048,1024]
    gemm_kernel<2048, 1024, 1024, 1, 0, 0, 1><<<256, 256, 0, stream>>>(
        key, nullptr, Wkh, Wkl, bk, kh, kl, nullptr, 1.f);
    // v^T = Wv value^T + bv (row bias)  [1024,2048]
    gemm_kernel<1024, 2048, 1024, 0, 1, 1, 1><<<256, 256, 0, stream>>>(
        Wvh, Wvl, value, nullptr, bv, vth, vtl, nullptr, 1.f);
    // fused attention -> obuf hi/lo     [2048,1024]
    flash_kernel<<<512, 256, 0, stream>>>(qh, ql, kh, kl, vth, vtl, attn_bias,
                                          masknorm, oh, ol);
    // out = obuf Wo^T + bo (fp32)       [2048,1024]
    gemm_kernel<2048, 1024, 1024, 0, 0, 0, 0><<<256, 256, 0, stream>>>(
        oh, ol, Woh, Wol, bo, nullptr, nullptr, out, 1.f);
}

// Round 4
// 370.567 us; speedup vs baseline: 1.7594x; 1.1957x over previous
//
#include <hip/hip_runtime.h>
#include <math.h>
#include <stdint.h>

#define B_ 2
#define T_ 1024
#define S_ 1024
#define E_ 1024
#define H_ 16
#define SCALING_ 0.125f

typedef short bf16x8 __attribute__((ext_vector_type(8)));   // 8 bf16 (4 VGPR) MFMA frag
typedef float f32x4 __attribute__((ext_vector_type(4)));    // MFMA acc frag
typedef unsigned short us8 __attribute__((ext_vector_type(8)));

__device__ __forceinline__ unsigned short f2bf(float x) {  // RNE fp32->bf16
    unsigned int u = __float_as_uint(x);
    return (unsigned short)((u + 0x7fffu + ((u >> 16) & 1u)) >> 16);
}
__device__ __forceinline__ float bf2f(unsigned short h) {
    return __uint_as_float(((unsigned int)h) << 16);
}
__device__ __forceinline__ void split_bf(float x, unsigned short& hh, unsigned short& ll) {
    hh = f2bf(x);
    ll = f2bf(x - bf2f(hh));
}
// async global->LDS, 16B per lane. LDS dest must be linear in lane order.
__device__ __forceinline__ void gl_lds16(const void* g, void* l) {
    __builtin_amdgcn_global_load_lds(
        (const __attribute__((address_space(1))) unsigned int*)g,
        (__attribute__((address_space(3))) unsigned int*)l, 16, 0, 0);
}

// ---------------------------------------------------------------------------
// Mask dtype detection + normalization (validated in rounds 1-2).
// ---------------------------------------------------------------------------
__global__ void mask_detect_kernel(const unsigned int* __restrict__ p,
                                   int* __restrict__ mode_out) {
    __shared__ int gt1_s, oddnz_s;
    if (threadIdx.x == 0) { gt1_s = 0; oddnz_s = 0; }
    __syncthreads();
    int gt1 = 0;
    for (int i = threadIdx.x; i < 512; i += 256)
        if (p[i] > 1u) gt1 = 1;
    if (gt1) atomicOr(&gt1_s, 1);
    __syncthreads();
    if (gt1_s == 0) {
        int oddnz = 0;
        for (int i = threadIdx.x; i < 2048; i += 256)
            if ((i & 1) && p[i] != 0u) oddnz = 1;
        if (oddnz) atomicOr(&oddnz_s, 1);
    }
    __syncthreads();
    if (threadIdx.x == 0)
        *mode_out = gt1_s ? 1 : (oddnz_s ? 0 : 2);
}

__global__ void mask_norm_kernel(const void* __restrict__ p,
                                 const int* __restrict__ mode_p,
                                 int* __restrict__ mout) {
    int i = blockIdx.x * 256 + threadIdx.x;  // 0..2047
    int mode = *mode_p;
    int v;
    if (mode == 1)      v = (int)((const unsigned char*)p)[i];
    else if (mode == 2) v = ((const int*)p)[2 * i];
    else                v = ((const int*)p)[i];
    mout[i] = v;
}

// ---------------------------------------------------------------------------
// fp32 -> (bf16 hi, bf16 lo) planar split for the 4 weight matrices, fused.
// grid 2048: w = blockIdx>>9 selects the weight.
// ---------------------------------------------------------------------------
__global__ __launch_bounds__(256) void conv_split4_kernel(
    const float* __restrict__ w0, const float* __restrict__ w1,
    const float* __restrict__ w2, const float* __restrict__ w3,
    unsigned short* __restrict__ d0h, unsigned short* __restrict__ d0l,
    unsigned short* __restrict__ d1h, unsigned short* __restrict__ d1l,
    unsigned short* __restrict__ d2h, unsigned short* __restrict__ d2l,
    unsigned short* __restrict__ d3h, unsigned short* __restrict__ d3l) {
    int w = blockIdx.x >> 9;
    int bid = blockIdx.x & 511;
    const float* src; unsigned short* dh; unsigned short* dl;
    if (w == 0)      { src = w0; dh = d0h; dl = d0l; }
    else if (w == 1) { src = w1; dh = d1h; dl = d1l; }
    else if (w == 2) { src = w2; dh = d2h; dl = d2l; }
    else             { src = w3; dh = d3h; dl = d3l; }
    int i = (bid * 256 + threadIdx.x) * 8;
    float4 a = *(const float4*)&src[i];
    float4 b = *(const float4*)&src[i + 4];
    float v[8] = {a.x, a.y, a.z, a.w, b.x, b.y, b.z, b.w};
    us8 vh, vl;
#pragma unroll
    for (int j = 0; j < 8; j++) {
        unsigned short hh, ll;
        split_bf(v[j], hh, ll);
        vh[j] = hh; vl[j] = ll;
    }
    *(us8*)&dh[i] = vh;
    *(us8*)&dl[i] = vl;
}

// ---------------------------------------------------------------------------
// Pipelined split-bf16 GEMM body: out[M,N] = alpha*(A[M,K].B[N,K]^T + bias)
// 128x64 tile, BK=32, 4 waves (2x2), 16x16x32 MFMA, 3-term split product.
// 2-phase schedule: issue stage(t+1) -> compute(t) -> vmcnt(0) [+split/write]
// -> barrier. LDS double-buffered (2 x 24KB), carved from `lds`.
// Chunk swizzle (rows of 64B = 4 chunks of 16B): chunk' = chunk ^ ((row>>1)&3)
// ---------------------------------------------------------------------------
template <int M, int N, int K, int A_F32, int B_F32, int ROWBIAS, int SPLITOUT>
__device__ __forceinline__ void gemm_body(
    int bid, const void* __restrict__ Aph, const void* __restrict__ Apl,
    const void* __restrict__ Bph, const void* __restrict__ Bpl,
    const float* __restrict__ bias,
    unsigned short* __restrict__ outh, unsigned short* __restrict__ outl,
    float* __restrict__ outf, float alpha, unsigned short* lds) {
    const int tid = threadIdx.x;
    const int lane = tid & 63;
    const int wave = tid >> 6;
    const int wm = wave >> 1, wn = wave & 1;
    const int bn = bid % (N / 64);
    const int bm = bid / (N / 64);
    const int m0 = bm * 128, n0 = bn * 64;
    const int srow = tid >> 2;   // staging row (0..63, +64 on pass 1)
    const int soct = tid & 3;    // staging k-octet
    constexpr int NT = K / 32;

    f32x4 acc[4][2];
#pragma unroll
    for (int i = 0; i < 4; i++)
#pragma unroll
        for (int j = 0; j < 2; j++) acc[i][j] = (f32x4){0.f, 0.f, 0.f, 0.f};

    // ---- prologue: stage tile 0 into buffer 0 ----
    {
        unsigned short* Ah = lds;
        unsigned short* Al = lds + 4096;
        unsigned short* Bh = lds + 8192;
        unsigned short* Bl = lds + 10240;
        if (A_F32) {
            const float* A = (const float*)Aph;
#pragma unroll
            for (int p = 0; p < 2; p++) {
                int row = p * 64 + srow;
                const float* s = &A[(size_t)(m0 + row) * K + soct * 8];
                float4 x = *(const float4*)s, y = *(const float4*)(s + 4);
                float v[8] = {x.x, x.y, x.z, x.w, y.x, y.y, y.z, y.w};
                us8 vh, vl;
#pragma unroll
                for (int j = 0; j < 8; j++) {
                    unsigned short hh, ll;
                    split_bf(v[j], hh, ll);
                    vh[j] = hh; vl[j] = ll;
                }
                int oct2 = soct ^ ((row >> 1) & 3);
                *(us8*)&Ah[row * 32 + oct2 * 8] = vh;
                *(us8*)&Al[row * 32 + oct2 * 8] = vl;
            }
        } else {
            const unsigned short* Ahg = (const unsigned short*)Aph;
            const unsigned short* Alg = (const unsigned short*)Apl;
#pragma unroll
            for (int p = 0; p < 2; p++) {
                int row = p * 64 + srow;
                int oct2 = soct ^ ((row >> 1) & 3);
                size_t g = (size_t)(m0 + row) * K + oct2 * 8;
                gl_lds16(&Ahg[g], &Ah[row * 32 + soct * 8]);
                gl_lds16(&Alg[g], &Al[row * 32 + soct * 8]);
            }
        }
        if (B_F32) {
            const float* Bv = (const float*)Bph;
            const float* s = &Bv[(size_t)(n0 + srow) * K + soct * 8];
            float4 x = *(const float4*)s, y = *(const float4*)(s + 4);
            float v[8] = {x.x, x.y, x.z, x.w, y.x, y.y, y.z, y.w};
            us8 vh, vl;
#pragma unroll
            for (int j = 0; j < 8; j++) {
                unsigned short hh, ll;
                split_bf(v[j], hh, ll);
                vh[j] = hh; vl[j] = ll;
            }
            int oct2 = soct ^ ((srow >> 1) & 3);
            *(us8*)&Bh[srow * 32 + oct2 * 8] = vh;
            *(us8*)&Bl[srow * 32 + oct2 * 8] = vl;
        } else {
            const unsigned short* Bhg = (const unsigned short*)Bph;
            const unsigned short* Blg = (const unsigned short*)Bpl;
            int oct2 = soct ^ ((srow >> 1) & 3);
            size_t g = (size_t)(n0 + srow) * K + oct2 * 8;
            gl_lds16(&Bhg[g], &Bh[srow * 32 + soct * 8]);
            gl_lds16(&Blg[g], &Bl[srow * 32 + soct * 8]);
        }
        asm volatile("s_waitcnt vmcnt(0)" ::: "memory");
    }
    __syncthreads();

    // ---- main loop: 2-phase pipeline ----
    for (int t = 0; t < NT; t++) {
        unsigned short* Ah = lds + (t & 1) * 12288;
        unsigned short* Al = Ah + 4096;
        unsigned short* Bh = Ah + 8192;
        unsigned short* Bl = Ah + 10240;
        unsigned short* nAh = lds + ((t & 1) ^ 1) * 12288;
        unsigned short* nAl = nAh + 4096;
        unsigned short* nBh = nAh + 8192;
        unsigned short* nBl = nAh + 10240;
        const int k1 = (t + 1) * 32;

        float4 apre[2][2];
        float4 bpre[2];
        // ---- issue next-tile loads (before compute) ----
        if (t + 1 < NT) {
            if (A_F32) {
                const float* A = (const float*)Aph;
#pragma unroll
                for (int p = 0; p < 2; p++) {
                    int row = p * 64 + srow;
                    const float* s = &A[(size_t)(m0 + row) * K + k1 + soct * 8];
                    apre[p][0] = *(const float4*)s;
                    apre[p][1] = *(const float4*)(s + 4);
                }
            } else {
                const unsigned short* Ahg = (const unsigned short*)Aph;
                const unsigned short* Alg = (const unsigned short*)Apl;
#pragma unroll
                for (int p = 0; p < 2; p++) {
                    int row = p * 64 + srow;
                    int oct2 = soct ^ ((row >> 1) & 3);
                    size_t g = (size_t)(m0 + row) * K + k1 + oct2 * 8;
                    gl_lds16(&Ahg[g], &nAh[row * 32 + soct * 8]);
                    gl_lds16(&Alg[g], &nAl[row * 32 + soct * 8]);
                }
            }
            if (B_F32) {
                const float* Bv = (const float*)Bph;
                const float* s = &Bv[(size_t)(n0 + srow) * K + k1 + soct * 8];
                bpre[0] = *(const float4*)s;
                bpre[1] = *(const float4*)(s + 4);
            } else {
                const unsigned short* Bhg = (const unsigned short*)Bph;
                const unsigned short* Blg = (const unsigned short*)Bpl;
                int oct2 = soct ^ ((srow >> 1) & 3);
                size_t g = (size_t)(n0 + srow) * K + k1 + oct2 * 8;
                gl_lds16(&Bhg[g], &nBh[srow * 32 + soct * 8]);
                gl_lds16(&Blg[g], &nBl[srow * 32 + soct * 8]);
            }
        }

        // ---- compute tile t: 24 MFMA / 12 ds_read_b128 per wave ----
        bf16x8 bh_[2], bl_[2];
#pragma unroll
        for (int nj = 0; nj < 2; nj++) {
            int rowB = wn * 32 + nj * 16 + (lane & 15);
            int ch = ((lane >> 4) ^ ((rowB >> 1) & 3));
            bh_[nj] = *(const bf16x8*)&Bh[rowB * 32 + ch * 8];
            bl_[nj] = *(const bf16x8*)&Bl[rowB * 32 + ch * 8];
        }
#pragma unroll
        for (int mi = 0; mi < 4; mi++) {
            int rowA = wm * 64 + mi * 16 + (lane & 15);
            int ch = ((lane >> 4) ^ ((rowA >> 1) & 3));
            bf16x8 afh = *(const bf16x8*)&Ah[rowA * 32 + ch * 8];
            bf16x8 afl = *(const bf16x8*)&Al[rowA * 32 + ch * 8];
#pragma unroll
            for (int nj = 0; nj < 2; nj++) {
                acc[mi][nj] = __builtin_amdgcn_mfma_f32_16x16x32_bf16(afh, bh_[nj], acc[mi][nj], 0, 0, 0);
                acc[mi][nj] = __builtin_amdgcn_mfma_f32_16x16x32_bf16(afl, bh_[nj], acc[mi][nj], 0, 0, 0);
                acc[mi][nj] = __builtin_amdgcn_mfma_f32_16x16x32_bf16(afh, bl_[nj], acc[mi][nj], 0, 0, 0);
            }
        }

        // ---- drain next-tile loads; fp32 paths: split + ds_write ----
        if (t + 1 < NT) {
            asm volatile("s_waitcnt vmcnt(0)" ::: "memory");
            if (A_F32) {
#pragma unroll
                for (int p = 0; p < 2; p++) {
                    int row = p * 64 + srow;
                    float v[8] = {apre[p][0].x, apre[p][0].y, apre[p][0].z, apre[p][0].w,
                                  apre[p][1].x, apre[p][1].y, apre[p][1].z, apre[p][1].w};
                    us8 vh, vl;
#pragma unroll
                    for (int j = 0; j < 8; j++) {
                        unsigned short hh, ll;
                        split_bf(v[j], hh, ll);
                        vh[j] = hh; vl[j] = ll;
                    }
                    int oct2 = soct ^ ((row >> 1) & 3);
                    *(us8*)&nAh[row * 32 + oct2 * 8] = vh;
                    *(us8*)&nAl[row * 32 + oct2 * 8] = vl;
                }
            }
            if (B_F32) {
                float v[8] = {bpre[0].x, bpre[0].y, bpre[0].z, bpre[0].w,
                              bpre[1].x, bpre[1].y, bpre[1].z, bpre[1].w};
                us8 vh, vl;
#pragma unroll
                for (int j = 0; j < 8; j++) {
                    unsigned short hh, ll;
                    split_bf(v[j], hh, ll);
                    vh[j] = hh; vl[j] = ll;
                }
                int oct2 = soct ^ ((srow >> 1) & 3);
                *(us8*)&nBh[srow * 32 + oct2 * 8] = vh;
                *(us8*)&nBl[srow * 32 + oct2 * 8] = vl;
            }
        }
        __syncthreads();
    }

    // ---- epilogue: bias, alpha, (split-)store ----
    float bcol[2];
    if (!ROWBIAS) {
#pragma unroll
        for (int nj = 0; nj < 2; nj++)
            bcol[nj] = bias[n0 + wn * 32 + nj * 16 + (lane & 15)];
    }
#pragma unroll
    for (int mi = 0; mi < 4; mi++) {
#pragma unroll
        for (int r = 0; r < 4; r++) {
            int row = m0 + wm * 64 + mi * 16 + (lane >> 4) * 4 + r;
            float brow = ROWBIAS ? bias[row] : 0.f;
#pragma unroll
            for (int nj = 0; nj < 2; nj++) {
                int col = n0 + wn * 32 + nj * 16 + (lane & 15);
                float v = alpha * (acc[mi][nj][r] + (ROWBIAS ? brow : bcol[nj]));
                if (SPLITOUT) {
                    unsigned short hh, ll;
                    split_bf(v, hh, ll);
                    outh[(size_t)row * N + col] = hh;
                    outl[(size_t)row * N + col] = ll;
                } else {
                    outf[(size_t)row * N + col] = v;
                }
            }
        }
    }
}

// Fused Q/K/V projections: 768 blocks, op = blockIdx>>8 (3 blocks/CU).
__global__ __launch_bounds__(256) void proj_fused_kernel(
    const float* __restrict__ query, const float* __restrict__ key,
    const float* __restrict__ value,
    const unsigned short* __restrict__ Wqh, const unsigned short* __restrict__ Wql,
    const unsigned short* __restrict__ Wkh, const unsigned short* __restrict__ Wkl,
    const unsigned short* __restrict__ Wvh, const unsigned short* __restrict__ Wvl,
    const float* __restrict__ bq, const float* __restrict__ bk,
    const float* __restrict__ bv_,
    unsigned short* __restrict__ qh, unsigned short* __restrict__ ql,
    unsigned short* __restrict__ kh, unsigned short* __restrict__ kl,
    unsigned short* __restrict__ vth, unsigned short* __restrict__ vtl) {
    __shared__ __align__(16) unsigned short lds[24576];
    int op = blockIdx.x >> 8;
    int bid = blockIdx.x & 255;
    if (op == 0)
        gemm_body<2048, 1024, 1024, 1, 0, 0, 1>(bid, query, nullptr, Wqh, Wql,
                                                bq, qh, ql, nullptr, SCALING_, lds);
    else if (op == 1)
        gemm_body<2048, 1024, 1024, 1, 0, 0, 1>(bid, key, nullptr, Wkh, Wkl,
                                                bk, kh, kl, nullptr, 1.f, lds);
    else
        gemm_body<1024, 2048, 1024, 0, 1, 1, 1>(bid, Wvh, Wvl, value, nullptr,
                                                bv_, vth, vtl, nullptr, 1.f, lds);
}

// Output projection: out = obuf . Wo^T + bo (fp32 out).
__global__ __launch_bounds__(256) void gemm_out_kernel(
    const unsigned short* __restrict__ oh, const unsigned short* __restrict__ ol,
    const unsigned short* __restrict__ Woh, const unsigned short* __restrict__ Wol,
    const float* __restrict__ bo, float* __restrict__ out) {
    __shared__ __align__(16) unsigned short lds[24576];
    gemm_body<2048, 1024, 1024, 0, 0, 0, 0>(blockIdx.x, oh, ol, Woh, Wol, bo,
                                            nullptr, nullptr, out, 1.f, lds);
}

// ---------------------------------------------------------------------------
// Flash attention, split-bf16 MFMA, 2-phase pipelined.
// Block = (b, h, 64 t-rows); 4 waves x 16 t. K/V LDS double-buffered; next
// tile's gl_lds issued before QK^T; next tile's bias/mask prefetched into
// regs after current use. q pre-scaled. V supplied TRANSPOSED ([E][B*S]).
// K/Q/Vt LDS rows 128B: chunk' = chunk ^ (row&7).
// P LDS (per wave, [16t][64s]): chunk' = chunk ^ f(t), f=((t>>2)&3)<<1|(t&1).
// ---------------------------------------------------------------------------
__global__ __launch_bounds__(256) void flash_kernel(
    const unsigned short* __restrict__ qh, const unsigned short* __restrict__ ql,
    const unsigned short* __restrict__ kh, const unsigned short* __restrict__ kl,
    const unsigned short* __restrict__ vth, const unsigned short* __restrict__ vtl,
    const float* __restrict__ bias, const int* __restrict__ mask,
    unsigned short* __restrict__ oh, unsigned short* __restrict__ ol) {
    __shared__ __align__(16) unsigned short Ksh[2][4096], Ksl[2][4096];
    __shared__ __align__(16) unsigned short Vsh[2][4096], Vsl[2][4096];
    __shared__ __align__(16) unsigned short Ph[4][1024], Pl[4][1024];

    const int tid = threadIdx.x;
    const int lane = tid & 63;
    const int wave = tid >> 6;
    const int bh = blockIdx.x >> 4;
    const int tt = blockIdx.x & 15;
    const int b = bh >> 4, h = bh & 15;
    const int t0 = tt * 64;
    const int srow = tid >> 3;  // staging row 0..31 (+32 pass 1)
    const int soct = tid & 7;   // staging d/s octet

    // ---- stage Q (into K buffer 0), hoist frags ----
#pragma unroll
    for (int p = 0; p < 2; p++) {
        int row = p * 32 + srow;
        int oct2 = soct ^ (row & 7);
        size_t g = (size_t)(b * T_ + t0 + row) * E_ + h * 64 + oct2 * 8;
        gl_lds16(&qh[g], &Ksh[0][row * 64 + soct * 8]);
        gl_lds16(&ql[g], &Ksl[0][row * 64 + soct * 8]);
    }
    asm volatile("s_waitcnt vmcnt(0)" ::: "memory");
    __syncthreads();
    bf16x8 qfh[2], qfl[2];
    {
        int row = wave * 16 + (lane & 15);
#pragma unroll
        for (int kk = 0; kk < 2; kk++) {
            int ch = (kk * 4 + (lane >> 4)) ^ (row & 7);
            qfh[kk] = *(const bf16x8*)&Ksh[0][row * 64 + ch * 8];
            qfl[kk] = *(const bf16x8*)&Ksl[0][row * 64 + ch * 8];
        }
    }
    __syncthreads();  // Q frag reads done before K staging overwrites

    float mrow[4] = {-INFINITY, -INFINITY, -INFINITY, -INFINITY};
    float lrow[4] = {0.f, 0.f, 0.f, 0.f};
    f32x4 oacc[4];
#pragma unroll
    for (int dj = 0; dj < 4; dj++) oacc[dj] = (f32x4){0.f, 0.f, 0.f, 0.f};

    const size_t bias0 = ((size_t)bh * T_ + t0 + wave * 16) * S_;

    // ---- prologue: stage K/V tile 0 into buf0, bias/mask tile 0 into regs
    float bv[4][4];
    int mk[4];
#pragma unroll
    for (int p = 0; p < 2; p++) {
        int row = p * 32 + srow;
        int oct2 = soct ^ (row & 7);
        size_t gk = (size_t)(b * S_ + row) * E_ + h * 64 + oct2 * 8;
        gl_lds16(&kh[gk], &Ksh[0][row * 64 + soct * 8]);
        gl_lds16(&kl[gk], &Ksl[0][row * 64 + soct * 8]);
        size_t gv = (size_t)(h * 64 + row) * (B_ * S_) + b * S_ + oct2 * 8;
        gl_lds16(&vth[gv], &Vsh[0][row * 64 + soct * 8]);
        gl_lds16(&vtl[gv], &Vsl[0][row * 64 + soct * 8]);
    }
#pragma unroll
    for (int nj = 0; nj < 4; nj++) {
        int s = nj * 16 + (lane & 15);
        mk[nj] = mask[b * S_ + s];
#pragma unroll
        for (int r = 0; r < 4; r++)
            bv[nj][r] = bias[bias0 + (size_t)((lane >> 4) * 4 + r) * S_ + s];
    }
    asm volatile("s_waitcnt vmcnt(0)" ::: "memory");
    __syncthreads();

    for (int s0i = 0; s0i < 16; s0i++) {
        const int s0 = s0i * 64;
        const int cur = s0i & 1;
        const int nxt = cur ^ 1;

        // ---- issue next K/V tile stage (overlaps compute) ----
        if (s0i < 15) {
            const int s0n = s0 + 64;
#pragma unroll
            for (int p = 0; p < 2; p++) {
                int row = p * 32 + srow;
                int oct2 = soct ^ (row & 7);
                size_t gk = (size_t)(b * S_ + s0n + row) * E_ + h * 64 + oct2 * 8;
                gl_lds16(&kh[gk], &Ksh[nxt][row * 64 + soct * 8]);
                gl_lds16(&kl[gk], &Ksl[nxt][row * 64 + soct * 8]);
                size_t gv = (size_t)(h * 64 + row) * (B_ * S_) + b * S_ + s0n + oct2 * 8;
                gl_lds16(&vth[gv], &Vsh[nxt][row * 64 + soct * 8]);
                gl_lds16(&vtl[gv], &Vsl[nxt][row * 64 + soct * 8]);
            }
        }

        // ---- QK^T (split 3-term) from buf[cur] ----
        f32x4 sc[4];
#pragma unroll
        for (int nj = 0; nj < 4; nj++) sc[nj] = (f32x4){0.f, 0.f, 0.f, 0.f};
#pragma unroll
        for (int kk = 0; kk < 2; kk++) {
#pragma unroll
            for (int nj = 0; nj < 4; nj++) {
                int row = nj * 16 + (lane & 15);
                int ch = (kk * 4 + (lane >> 4)) ^ (row & 7);
                bf16x8 kfh = *(const bf16x8*)&Ksh[cur][row * 64 + ch * 8];
                bf16x8 kfl = *(const bf16x8*)&Ksl[cur][row * 64 + ch * 8];
                sc[nj] = __builtin_amdgcn_mfma_f32_16x16x32_bf16(qfh[kk], kfh, sc[nj], 0, 0, 0);
                sc[nj] = __builtin_amdgcn_mfma_f32_16x16x32_bf16(qfl[kk], kfh, sc[nj], 0, 0, 0);
                sc[nj] = __builtin_amdgcn_mfma_f32_16x16x32_bf16(qfh[kk], kfl, sc[nj], 0, 0, 0);
            }
        }
        // mask -> -inf (BEFORE bias add, matches reference), then + bias
#pragma unroll
        for (int nj = 0; nj < 4; nj++)
#pragma unroll
            for (int r = 0; r < 4; r++) {
                float v = mk[nj] ? -INFINITY : sc[nj][r];
                sc[nj][r] = v + bv[nj][r];
            }

        // ---- prefetch next tile's bias/mask into regs (after last use) ----
        if (s0i < 15) {
            const int s0n = s0 + 64;
#pragma unroll
            for (int nj = 0; nj < 4; nj++) {
                int s = s0n + nj * 16 + (lane & 15);
                mk[nj] = mask[b * S_ + s];
#pragma unroll
                for (int r = 0; r < 4; r++)
                    bv[nj][r] = bias[bias0 + (size_t)((lane >> 4) * 4 + r) * S_ + s];
            }
        }

        // ---- online softmax (per r = t-row), all in registers ----
        unsigned short phv[4][4], plv[4][4];
#pragma unroll
        for (int r = 0; r < 4; r++) {
            float mx = fmaxf(fmaxf(sc[0][r], sc[1][r]), fmaxf(sc[2][r], sc[3][r]));
            mx = fmaxf(mx, __shfl_xor(mx, 1));
            mx = fmaxf(mx, __shfl_xor(mx, 2));
            mx = fmaxf(mx, __shfl_xor(mx, 4));
            mx = fmaxf(mx, __shfl_xor(mx, 8));
            float mnew = fmaxf(mrow[r], mx);
            float esc = __expf(mrow[r] - mnew);  // first tile: exp(-inf)=0
            float ps = 0.f;
#pragma unroll
            for (int nj = 0; nj < 4; nj++) {
                float p = __expf(sc[nj][r] - mnew);  // masked: exp(-inf)=0
                ps += p;
                split_bf(p, phv[nj][r], plv[nj][r]);
            }
            ps += __shfl_xor(ps, 1);
            ps += __shfl_xor(ps, 2);
            ps += __shfl_xor(ps, 4);
            ps += __shfl_xor(ps, 8);
            lrow[r] = lrow[r] * esc + ps;
            mrow[r] = mnew;
#pragma unroll
            for (int dj = 0; dj < 4; dj++) oacc[dj][r] *= esc;
        }

        // ---- write P (hi/lo) to per-wave swizzled LDS ----
#pragma unroll
        for (int r = 0; r < 4; r++) {
            int t = (lane >> 4) * 4 + r;
            int f = (((t >> 2) & 3) << 1) | (t & 1);
#pragma unroll
            for (int nj = 0; nj < 4; nj++) {
                int s = nj * 16 + (lane & 15);
                int idx = t * 64 + (((s >> 3) ^ f) * 8) + (s & 7);
                Ph[wave][idx] = phv[nj][r];
                Pl[wave][idx] = plv[nj][r];
            }
        }
        // ---- PV (split 3-term) from buf[cur] ----
        bf16x8 pah[2], pal[2];
        {
            int t = lane & 15;
            int f = (((t >> 2) & 3) << 1) | (t & 1);
#pragma unroll
            for (int kk = 0; kk < 2; kk++) {
                int ch = (kk * 4 + (lane >> 4)) ^ f;
                pah[kk] = *(const bf16x8*)&Ph[wave][t * 64 + ch * 8];
                pal[kk] = *(const bf16x8*)&Pl[wave][t * 64 + ch * 8];
            }
        }
#pragma unroll
        for (int dj = 0; dj < 4; dj++) {
            int row = dj * 16 + (lane & 15);
#pragma unroll
            for (int kk = 0; kk < 2; kk++) {
                int ch = (kk * 4 + (lane >> 4)) ^ (row & 7);
                bf16x8 vfh = *(const bf16x8*)&Vsh[cur][row * 64 + ch * 8];
                bf16x8 vfl = *(const bf16x8*)&Vsl[cur][row * 64 + ch * 8];
                oacc[dj] = __builtin_amdgcn_mfma_f32_16x16x32_bf16(pah[kk], vfh, oacc[dj], 0, 0, 0);
                oacc[dj] = __builtin_amdgcn_mfma_f32_16x16x32_bf16(pal[kk], vfh, oacc[dj], 0, 0, 0);
                oacc[dj] = __builtin_amdgcn_mfma_f32_16x16x32_bf16(pah[kk], vfl, oacc[dj], 0, 0, 0);
            }
        }

        // ---- drain next-tile stage + bias prefetch; swap ----
        asm volatile("s_waitcnt vmcnt(0)" ::: "memory");
        __syncthreads();
    }

    // ---- epilogue: O = acc / l, split-store to obuf ----
#pragma unroll
    for (int r = 0; r < 4; r++) {
        float inv = 1.f / lrow[r];
        int t = t0 + wave * 16 + (lane >> 4) * 4 + r;
#pragma unroll
        for (int dj = 0; dj < 4; dj++) {
            float v = oacc[dj][r] * inv;
            unsigned short hh, ll;
            split_bf(v, hh, ll);
            size_t g = (size_t)(b * T_ + t) * E_ + h * 64 + dj * 16 + (lane & 15);
            oh[g] = hh;
            ol[g] = ll;
        }
    }
}

// ---------------------------------------------------------------------------
extern "C" void kernel_launch(void* const* d_in, const int* in_sizes, int n_in,
                              void* d_out, int out_size, void* d_ws,
                              size_t ws_size, hipStream_t stream) {
    const float* query = (const float*)d_in[0];
    const float* key   = (const float*)d_in[1];
    const float* value = (const float*)d_in[2];
    const void*  kpm   = d_in[3];
    const float* attn_bias = (const float*)d_in[4];
    const float* Wq = (const float*)d_in[5];
    const float* bq = (const float*)d_in[6];
    const float* Wk = (const float*)d_in[7];
    const float* bk = (const float*)d_in[8];
    const float* Wv = (const float*)d_in[9];
    const float* bv = (const float*)d_in[10];
    const float* Wo = (const float*)d_in[11];
    const float* bo = (const float*)d_in[12];
    float* out = (float*)d_out;

    char* ws = (char*)d_ws;
    const size_t MB = 1024 * 1024;
    unsigned short* Wqh = (unsigned short*)(ws + 0 * MB);
    unsigned short* Wql = (unsigned short*)(ws + 2 * MB);
    unsigned short* Wkh = (unsigned short*)(ws + 4 * MB);
    unsigned short* Wkl = (unsigned short*)(ws + 6 * MB);
    unsigned short* Wvh = (unsigned short*)(ws + 8 * MB);
    unsigned short* Wvl = (unsigned short*)(ws + 10 * MB);
    unsigned short* Woh = (unsigned short*)(ws + 12 * MB);
    unsigned short* Wol = (unsigned short*)(ws + 14 * MB);
    unsigned short* qh = (unsigned short*)(ws + 16 * MB);
    unsigned short* ql = (unsigned short*)(ws + 20 * MB);
    unsigned short* kh = (unsigned short*)(ws + 24 * MB);
    unsigned short* kl = (unsigned short*)(ws + 28 * MB);
    unsigned short* vth = (unsigned short*)(ws + 32 * MB);  // V^T [E][B*S]
    unsigned short* vtl = (unsigned short*)(ws + 36 * MB);
    unsigned short* oh = (unsigned short*)(ws + 0 * MB);    // overlays Wq/Wk
    unsigned short* ol = (unsigned short*)(ws + 4 * MB);
    int* masknorm = (int*)(ws + 40 * MB);
    int* mode = masknorm + 2048;

    conv_split4_kernel<<<2048, 256, 0, stream>>>(Wq, Wk, Wv, Wo,
        Wqh, Wql, Wkh, Wkl, Wvh, Wvl, Woh, Wol);
    mask_detect_kernel<<<1, 256, 0, stream>>>((const unsigned int*)kpm, mode);
    mask_norm_kernel<<<8, 256, 0, stream>>>(kpm, mode, masknorm);

    // q/k/v projections fused (SCALING folded into q); v computed transposed.
    proj_fused_kernel<<<768, 256, 0, stream>>>(
        query, key, value, Wqh, Wql, Wkh, Wkl, Wvh, Wvl, bq, bk, bv,
        qh, ql, kh, kl, vth, vtl);

    // fused attention -> obuf hi/lo
    flash_kernel<<<512, 256, 0, stream>>>(qh, ql, kh, kl, vth, vtl, attn_bias,
                                          masknorm, oh, ol);

    // out = obuf . Wo^T + bo (fp32)
    gemm_out_kernel<<<256, 256, 0, stream>>>(oh, ol, Woh, Wol, bo, out);
}

// Round 5
// 339.347 us; speedup vs baseline: 1.9213x; 1.0920x over previous
//
#include <hip/hip_runtime.h>
#include <math.h>
#include <stdint.h>

#define B_ 2
#define T_ 1024
#define S_ 1024
#define E_ 1024
#define H_ 16
#define SCALING_ 0.125f

typedef short bf16x8 __attribute__((ext_vector_type(8)));   // 8 bf16 (4 VGPR) MFMA frag
typedef float f32x4 __attribute__((ext_vector_type(4)));    // MFMA acc frag
typedef unsigned short us8 __attribute__((ext_vector_type(8)));

__device__ __forceinline__ unsigned short f2bf(float x) {  // RNE fp32->bf16
    unsigned int u = __float_as_uint(x);
    return (unsigned short)((u + 0x7fffu + ((u >> 16) & 1u)) >> 16);
}
__device__ __forceinline__ float bf2f(unsigned short h) {
    return __uint_as_float(((unsigned int)h) << 16);
}
__device__ __forceinline__ void split_bf(float x, unsigned short& hh, unsigned short& ll) {
    hh = f2bf(x);
    ll = f2bf(x - bf2f(hh));
}
// async global->LDS, 16B per lane. LDS dest must be linear in lane order.
__device__ __forceinline__ void gl_lds16(const void* g, void* l) {
    __builtin_amdgcn_global_load_lds(
        (const __attribute__((address_space(1))) unsigned int*)g,
        (__attribute__((address_space(3))) unsigned int*)l, 16, 0, 0);
}
// DPP row_ror rotate (within 16-lane rows), VALU-speed cross-lane.
template <int CTRL>
__device__ __forceinline__ float dpp_ror(float x) {
    int v = __builtin_amdgcn_update_dpp(0, __float_as_int(x), CTRL, 0xf, 0xf, true);
    return __int_as_float(v);
}

// ---------------------------------------------------------------------------
// Mask dtype detection + normalization (validated rounds 1-4).
// ---------------------------------------------------------------------------
__global__ void mask_detect_kernel(const unsigned int* __restrict__ p,
                                   int* __restrict__ mode_out) {
    __shared__ int gt1_s, oddnz_s;
    if (threadIdx.x == 0) { gt1_s = 0; oddnz_s = 0; }
    __syncthreads();
    int gt1 = 0;
    for (int i = threadIdx.x; i < 512; i += 256)
        if (p[i] > 1u) gt1 = 1;
    if (gt1) atomicOr(&gt1_s, 1);
    __syncthreads();
    if (gt1_s == 0) {
        int oddnz = 0;
        for (int i = threadIdx.x; i < 2048; i += 256)
            if ((i & 1) && p[i] != 0u) oddnz = 1;
        if (oddnz) atomicOr(&oddnz_s, 1);
    }
    __syncthreads();
    if (threadIdx.x == 0)
        *mode_out = gt1_s ? 1 : (oddnz_s ? 0 : 2);
}

__global__ void mask_norm_kernel(const void* __restrict__ p,
                                 const int* __restrict__ mode_p,
                                 int* __restrict__ mout) {
    int i = blockIdx.x * 256 + threadIdx.x;  // 0..2047
    int mode = *mode_p;
    int v;
    if (mode == 1)      v = (int)((const unsigned char*)p)[i];
    else if (mode == 2) v = ((const int*)p)[2 * i];
    else                v = ((const int*)p)[i];
    mout[i] = v;
}

// ---------------------------------------------------------------------------
// fp32 -> (bf16 hi, bf16 lo) planar split: 4 weights (1M elems each) +
// 3 activations (2M elems each). grid 5120.
// ---------------------------------------------------------------------------
__global__ __launch_bounds__(256) void conv_split7_kernel(
    const float* __restrict__ Wq, const float* __restrict__ Wk,
    const float* __restrict__ Wv, const float* __restrict__ Wo,
    const float* __restrict__ xq, const float* __restrict__ xk,
    const float* __restrict__ xv,
    unsigned short* __restrict__ Wqh, unsigned short* __restrict__ Wql,
    unsigned short* __restrict__ Wkh, unsigned short* __restrict__ Wkl,
    unsigned short* __restrict__ Wvh, unsigned short* __restrict__ Wvl,
    unsigned short* __restrict__ Woh, unsigned short* __restrict__ Wol,
    unsigned short* __restrict__ xqh, unsigned short* __restrict__ xql,
    unsigned short* __restrict__ xkh, unsigned short* __restrict__ xkl,
    unsigned short* __restrict__ xvh, unsigned short* __restrict__ xvl) {
    int bid = blockIdx.x;
    const float* src; unsigned short* dh; unsigned short* dl; int lb;
    if (bid < 2048) {
        int w = bid >> 9; lb = bid & 511;
        if (w == 0)      { src = Wq; dh = Wqh; dl = Wql; }
        else if (w == 1) { src = Wk; dh = Wkh; dl = Wkl; }
        else if (w == 2) { src = Wv; dh = Wvh; dl = Wvl; }
        else             { src = Wo; dh = Woh; dl = Wol; }
    } else {
        int a = (bid - 2048) >> 10; lb = (bid - 2048) & 1023;
        if (a == 0)      { src = xq; dh = xqh; dl = xql; }
        else if (a == 1) { src = xk; dh = xkh; dl = xkl; }
        else             { src = xv; dh = xvh; dl = xvl; }
    }
    int i = (lb * 256 + threadIdx.x) * 8;
    float4 a4 = *(const float4*)&src[i];
    float4 b4 = *(const float4*)&src[i + 4];
    float v[8] = {a4.x, a4.y, a4.z, a4.w, b4.x, b4.y, b4.z, b4.w};
    us8 vh, vl;
#pragma unroll
    for (int j = 0; j < 8; j++) {
        unsigned short hh, ll;
        split_bf(v[j], hh, ll);
        vh[j] = hh; vl[j] = ll;
    }
    *(us8*)&dh[i] = vh;
    *(us8*)&dl[i] = vl;
}

// ---------------------------------------------------------------------------
// Split-bf16 GEMM body (pure gl_lds): out[*,N] = alpha*(A . B^T + bias)
// Tile BM x 64, NW waves (NW/2 m-groups x 2 n-groups), each wave 32x32 out.
// BK=32, 16x16x32 MFMA, 3-term split product. 2-phase pipeline, dbuf LDS.
// Chunk swizzle (rows of 64B = 4 x 16B): chunk' = chunk ^ ((row>>1)&3).
// ---------------------------------------------------------------------------
template <int BM, int NW, int N, int K, int ROWBIAS, int SPLITOUT>
__device__ __forceinline__ void gemm_body2(
    int bid,
    const unsigned short* __restrict__ Ahg, const unsigned short* __restrict__ Alg,
    const unsigned short* __restrict__ Bhg, const unsigned short* __restrict__ Blg,
    const float* __restrict__ bias,
    unsigned short* __restrict__ outh, unsigned short* __restrict__ outl,
    float* __restrict__ outf, float alpha, unsigned short* lds) {
    const int tid = threadIdx.x;
    const int lane = tid & 63;
    const int wave = tid >> 6;
    const int wm = wave >> 1, wn = wave & 1;
    const int bn = bid % (N / 64);
    const int bm = bid / (N / 64);
    const int m0 = bm * BM, n0 = bn * 64;
    constexpr int NT = K / 32;
    constexpr int ABUF = BM * 32;          // elems per A plane
    constexpr int BUFE = 2 * ABUF + 4096;  // elems per buffer
    const int arow = tid >> 2, aoct = tid & 3;

    f32x4 acc[2][2];
#pragma unroll
    for (int i = 0; i < 2; i++)
#pragma unroll
        for (int j = 0; j < 2; j++) acc[i][j] = (f32x4){0.f, 0.f, 0.f, 0.f};

    auto stage = [&](int k0, unsigned short* buf) {
        // A: one 16B slot per thread per plane
        int ao2 = aoct ^ ((arow >> 1) & 3);
        size_t ga = (size_t)(m0 + arow) * K + k0 + ao2 * 8;
        gl_lds16(&Ahg[ga], &buf[arow * 32 + aoct * 8]);
        gl_lds16(&Alg[ga], &buf[ABUF + arow * 32 + aoct * 8]);
        // B: 64x32 per plane
        if (NW == 8) {  // half threads -> Bh, half -> Bl
            int bslot = tid & 255;
            int brow = bslot >> 2, boct = bslot & 3;
            int bo2 = boct ^ ((brow >> 1) & 3);
            size_t gb = (size_t)(n0 + brow) * K + k0 + bo2 * 8;
            const unsigned short* src = (tid < 256) ? Bhg : Blg;
            gl_lds16(&src[gb],
                     &buf[2 * ABUF + (tid < 256 ? 0 : 2048) + bslot * 8]);
        } else {  // NW==4: every thread does both planes
            int brow = tid >> 2, boct = tid & 3;
            int bo2 = boct ^ ((brow >> 1) & 3);
            size_t gb = (size_t)(n0 + brow) * K + k0 + bo2 * 8;
            gl_lds16(&Bhg[gb], &buf[2 * ABUF + tid * 8]);
            gl_lds16(&Blg[gb], &buf[2 * ABUF + 2048 + tid * 8]);
        }
    };

    // prologue
    stage(0, lds);
    asm volatile("s_waitcnt vmcnt(0)" ::: "memory");
    __syncthreads();

    for (int t = 0; t < NT; t++) {
        unsigned short* cur = lds + (t & 1) * BUFE;
        unsigned short* nxt = lds + ((t & 1) ^ 1) * BUFE;
        if (t + 1 < NT) stage((t + 1) * 32, nxt);

        bf16x8 af[2][2], bf_[2][2];
#pragma unroll
        for (int nj = 0; nj < 2; nj++) {
            int rowB = wn * 32 + nj * 16 + (lane & 15);
            int ch = (lane >> 4) ^ ((rowB >> 1) & 3);
            bf_[nj][0] = *(const bf16x8*)&cur[2 * ABUF + rowB * 32 + ch * 8];
            bf_[nj][1] = *(const bf16x8*)&cur[2 * ABUF + 2048 + rowB * 32 + ch * 8];
        }
#pragma unroll
        for (int mi = 0; mi < 2; mi++) {
            int rowA = wm * 32 + mi * 16 + (lane & 15);
            int ch = (lane >> 4) ^ ((rowA >> 1) & 3);
            af[mi][0] = *(const bf16x8*)&cur[rowA * 32 + ch * 8];
            af[mi][1] = *(const bf16x8*)&cur[ABUF + rowA * 32 + ch * 8];
        }
#pragma unroll
        for (int mi = 0; mi < 2; mi++)
#pragma unroll
            for (int nj = 0; nj < 2; nj++) {
                acc[mi][nj] = __builtin_amdgcn_mfma_f32_16x16x32_bf16(af[mi][0], bf_[nj][0], acc[mi][nj], 0, 0, 0);
                acc[mi][nj] = __builtin_amdgcn_mfma_f32_16x16x32_bf16(af[mi][1], bf_[nj][0], acc[mi][nj], 0, 0, 0);
                acc[mi][nj] = __builtin_amdgcn_mfma_f32_16x16x32_bf16(af[mi][0], bf_[nj][1], acc[mi][nj], 0, 0, 0);
            }

        asm volatile("s_waitcnt vmcnt(0)" ::: "memory");
        __syncthreads();
    }

    // epilogue
    float bcol[2];
    if (!ROWBIAS) {
#pragma unroll
        for (int nj = 0; nj < 2; nj++)
            bcol[nj] = bias[n0 + wn * 32 + nj * 16 + (lane & 15)];
    }
#pragma unroll
    for (int mi = 0; mi < 2; mi++) {
#pragma unroll
        for (int r = 0; r < 4; r++) {
            int row = m0 + wm * 32 + mi * 16 + (lane >> 4) * 4 + r;
            float brow = ROWBIAS ? bias[row] : 0.f;
#pragma unroll
            for (int nj = 0; nj < 2; nj++) {
                int col = n0 + wn * 32 + nj * 16 + (lane & 15);
                float v = alpha * (acc[mi][nj][r] + (ROWBIAS ? brow : bcol[nj]));
                if (SPLITOUT) {
                    unsigned short hh, ll;
                    split_bf(v, hh, ll);
                    outh[(size_t)row * N + col] = hh;
                    outl[(size_t)row * N + col] = ll;
                } else {
                    outf[(size_t)row * N + col] = v;
                }
            }
        }
    }
}

// Fused Q/K/V projections: 768 blocks x 512 threads (3 blocks/CU, 24 w/CU).
__global__ __launch_bounds__(512, 4) void proj_fused_kernel(
    const unsigned short* __restrict__ xqh, const unsigned short* __restrict__ xql,
    const unsigned short* __restrict__ xkh, const unsigned short* __restrict__ xkl,
    const unsigned short* __restrict__ xvh, const unsigned short* __restrict__ xvl,
    const unsigned short* __restrict__ Wqh, const unsigned short* __restrict__ Wql,
    const unsigned short* __restrict__ Wkh, const unsigned short* __restrict__ Wkl,
    const unsigned short* __restrict__ Wvh, const unsigned short* __restrict__ Wvl,
    const float* __restrict__ bq, const float* __restrict__ bk,
    const float* __restrict__ bv_,
    unsigned short* __restrict__ qh, unsigned short* __restrict__ ql,
    unsigned short* __restrict__ kh, unsigned short* __restrict__ kl,
    unsigned short* __restrict__ vth, unsigned short* __restrict__ vtl) {
    __shared__ __align__(16) unsigned short lds[2 * (2 * 128 * 32 + 4096)];
    int op = blockIdx.x >> 8;
    int bid = blockIdx.x & 255;
    if (op == 0)
        gemm_body2<128, 8, 1024, 1024, 0, 1>(bid, xqh, xql, Wqh, Wql, bq,
                                             qh, ql, nullptr, SCALING_, lds);
    else if (op == 1)
        gemm_body2<128, 8, 1024, 1024, 0, 1>(bid, xkh, xkl, Wkh, Wkl, bk,
                                             kh, kl, nullptr, 1.f, lds);
    else  // v^T = Wv . value^T + bv(row): A = Wv planes, B = value planes
        gemm_body2<128, 8, 2048, 1024, 1, 1>(bid, Wvh, Wvl, xvh, xvl, bv_,
                                             vth, vtl, nullptr, 1.f, lds);
}

// Output projection: 64x64 tile, 4 waves, grid 512 (2 blocks/CU).
__global__ __launch_bounds__(256) void gemm_out_kernel(
    const unsigned short* __restrict__ oh, const unsigned short* __restrict__ ol,
    const unsigned short* __restrict__ Woh, const unsigned short* __restrict__ Wol,
    const float* __restrict__ bo, float* __restrict__ out) {
    __shared__ __align__(16) unsigned short lds[2 * (2 * 64 * 32 + 4096)];
    gemm_body2<64, 4, 1024, 1024, 0, 0>(blockIdx.x, oh, ol, Woh, Wol, bo,
                                        nullptr, nullptr, out, 1.f, lds);
}

// ---------------------------------------------------------------------------
// Flash attention, split-bf16 MFMA, 2-phase pipelined, DPP-reduce softmax.
// Block = (b, h, 64 t-rows); 4 waves x 16 t. K/V LDS double-buffered.
// q pre-scaled. V supplied TRANSPOSED ([E][B*S]).
// K/Q/Vt LDS rows 128B: chunk' = chunk ^ (row&7).
// P LDS (per wave, [16t][64s]): chunk' = chunk ^ f(t), f=((t>>2)&3)<<1|(t&1).
// ---------------------------------------------------------------------------
__global__ __launch_bounds__(256) void flash_kernel(
    const unsigned short* __restrict__ qh, const unsigned short* __restrict__ ql,
    const unsigned short* __restrict__ kh, const unsigned short* __restrict__ kl,
    const unsigned short* __restrict__ vth, const unsigned short* __restrict__ vtl,
    const float* __restrict__ bias, const int* __restrict__ mask,
    unsigned short* __restrict__ oh, unsigned short* __restrict__ ol) {
    __shared__ __align__(16) unsigned short Ksh[2][4096], Ksl[2][4096];
    __shared__ __align__(16) unsigned short Vsh[2][4096], Vsl[2][4096];
    __shared__ __align__(16) unsigned short Ph[4][1024], Pl[4][1024];

    const int tid = threadIdx.x;
    const int lane = tid & 63;
    const int wave = tid >> 6;
    const int bh = blockIdx.x >> 4;
    const int tt = blockIdx.x & 15;
    const int b = bh >> 4, h = bh & 15;
    const int t0 = tt * 64;
    const int srow = tid >> 3;  // staging row 0..31 (+32 pass 1)
    const int soct = tid & 7;   // staging d/s octet

    // ---- stage Q (into K buffer 0), hoist frags ----
#pragma unroll
    for (int p = 0; p < 2; p++) {
        int row = p * 32 + srow;
        int oct2 = soct ^ (row & 7);
        size_t g = (size_t)(b * T_ + t0 + row) * E_ + h * 64 + oct2 * 8;
        gl_lds16(&qh[g], &Ksh[0][row * 64 + soct * 8]);
        gl_lds16(&ql[g], &Ksl[0][row * 64 + soct * 8]);
    }
    asm volatile("s_waitcnt vmcnt(0)" ::: "memory");
    __syncthreads();
    bf16x8 qfh[2], qfl[2];
    {
        int row = wave * 16 + (lane & 15);
#pragma unroll
        for (int kk = 0; kk < 2; kk++) {
            int ch = (kk * 4 + (lane >> 4)) ^ (row & 7);
            qfh[kk] = *(const bf16x8*)&Ksh[0][row * 64 + ch * 8];
            qfl[kk] = *(const bf16x8*)&Ksl[0][row * 64 + ch * 8];
        }
    }
    __syncthreads();  // Q frag reads done before K staging overwrites

    float mrow[4] = {-INFINITY, -INFINITY, -INFINITY, -INFINITY};
    float lrow[4] = {0.f, 0.f, 0.f, 0.f};
    f32x4 oacc[4];
#pragma unroll
    for (int dj = 0; dj < 4; dj++) oacc[dj] = (f32x4){0.f, 0.f, 0.f, 0.f};

    const size_t bias0 = ((size_t)bh * T_ + t0 + wave * 16) * S_;

    // ---- prologue: stage K/V tile 0 into buf0, bias/mask tile 0 into regs
    float bv[4][4];
    int mk[4];
#pragma unroll
    for (int p = 0; p < 2; p++) {
        int row = p * 32 + srow;
        int oct2 = soct ^ (row & 7);
        size_t gk = (size_t)(b * S_ + row) * E_ + h * 64 + oct2 * 8;
        gl_lds16(&kh[gk], &Ksh[0][row * 64 + soct * 8]);
        gl_lds16(&kl[gk], &Ksl[0][row * 64 + soct * 8]);
        size_t gv = (size_t)(h * 64 + row) * (B_ * S_) + b * S_ + oct2 * 8;
        gl_lds16(&vth[gv], &Vsh[0][row * 64 + soct * 8]);
        gl_lds16(&vtl[gv], &Vsl[0][row * 64 + soct * 8]);
    }
#pragma unroll
    for (int nj = 0; nj < 4; nj++) {
        int s = nj * 16 + (lane & 15);
        mk[nj] = mask[b * S_ + s];
#pragma unroll
        for (int r = 0; r < 4; r++)
            bv[nj][r] = bias[bias0 + (size_t)((lane >> 4) * 4 + r) * S_ + s];
    }
    asm volatile("s_waitcnt vmcnt(0)" ::: "memory");
    __syncthreads();

    for (int s0i = 0; s0i < 16; s0i++) {
        const int s0 = s0i * 64;
        const int cur = s0i & 1;
        const int nxt = cur ^ 1;

        // ---- issue next K/V tile stage (overlaps compute) ----
        if (s0i < 15) {
            const int s0n = s0 + 64;
#pragma unroll
            for (int p = 0; p < 2; p++) {
                int row = p * 32 + srow;
                int oct2 = soct ^ (row & 7);
                size_t gk = (size_t)(b * S_ + s0n + row) * E_ + h * 64 + oct2 * 8;
                gl_lds16(&kh[gk], &Ksh[nxt][row * 64 + soct * 8]);
                gl_lds16(&kl[gk], &Ksl[nxt][row * 64 + soct * 8]);
                size_t gv = (size_t)(h * 64 + row) * (B_ * S_) + b * S_ + s0n + oct2 * 8;
                gl_lds16(&vth[gv], &Vsh[nxt][row * 64 + soct * 8]);
                gl_lds16(&vtl[gv], &Vsl[nxt][row * 64 + soct * 8]);
            }
        }

        // ---- QK^T (split 3-term) from buf[cur] ----
        f32x4 sc[4];
#pragma unroll
        for (int nj = 0; nj < 4; nj++) sc[nj] = (f32x4){0.f, 0.f, 0.f, 0.f};
#pragma unroll
        for (int kk = 0; kk < 2; kk++) {
#pragma unroll
            for (int nj = 0; nj < 4; nj++) {
                int row = nj * 16 + (lane & 15);
                int ch = (kk * 4 + (lane >> 4)) ^ (row & 7);
                bf16x8 kfh = *(const bf16x8*)&Ksh[cur][row * 64 + ch * 8];
                bf16x8 kfl = *(const bf16x8*)&Ksl[cur][row * 64 + ch * 8];
                sc[nj] = __builtin_amdgcn_mfma_f32_16x16x32_bf16(qfh[kk], kfh, sc[nj], 0, 0, 0);
                sc[nj] = __builtin_amdgcn_mfma_f32_16x16x32_bf16(qfl[kk], kfh, sc[nj], 0, 0, 0);
                sc[nj] = __builtin_amdgcn_mfma_f32_16x16x32_bf16(qfh[kk], kfl, sc[nj], 0, 0, 0);
            }
        }
        // mask -> -inf (BEFORE bias add, matches reference), then + bias
#pragma unroll
        for (int nj = 0; nj < 4; nj++)
#pragma unroll
            for (int r = 0; r < 4; r++) {
                float v = mk[nj] ? -INFINITY : sc[nj][r];
                sc[nj][r] = v + bv[nj][r];
            }

        // ---- prefetch next tile's bias/mask into regs (after last use) ----
        if (s0i < 15) {
            const int s0n = s0 + 64;
#pragma unroll
            for (int nj = 0; nj < 4; nj++) {
                int s = s0n + nj * 16 + (lane & 15);
                mk[nj] = mask[b * S_ + s];
#pragma unroll
                for (int r = 0; r < 4; r++)
                    bv[nj][r] = bias[bias0 + (size_t)((lane >> 4) * 4 + r) * S_ + s];
            }
        }

        // ---- online softmax (per r = t-row), DPP rotate-reduce over 16 lanes
        unsigned short phv[4][4], plv[4][4];
#pragma unroll
        for (int r = 0; r < 4; r++) {
            float mx = fmaxf(fmaxf(sc[0][r], sc[1][r]), fmaxf(sc[2][r], sc[3][r]));
            mx = fmaxf(mx, dpp_ror<0x121>(mx));
            mx = fmaxf(mx, dpp_ror<0x122>(mx));
            mx = fmaxf(mx, dpp_ror<0x124>(mx));
            mx = fmaxf(mx, dpp_ror<0x128>(mx));
            float mnew = fmaxf(mrow[r], mx);
            float esc = __expf(mrow[r] - mnew);  // first tile: exp(-inf)=0
            float ps = 0.f;
#pragma unroll
            for (int nj = 0; nj < 4; nj++) {
                float p = __expf(sc[nj][r] - mnew);  // masked: exp(-inf)=0
                ps += p;
                split_bf(p, phv[nj][r], plv[nj][r]);
            }
            ps += dpp_ror<0x121>(ps);
            ps += dpp_ror<0x122>(ps);
            ps += dpp_ror<0x124>(ps);
            ps += dpp_ror<0x128>(ps);
            lrow[r] = lrow[r] * esc + ps;
            mrow[r] = mnew;
#pragma unroll
            for (int dj = 0; dj < 4; dj++) oacc[dj][r] *= esc;
        }

        // ---- write P (hi/lo) to per-wave swizzled LDS ----
#pragma unroll
        for (int r = 0; r < 4; r++) {
            int t = (lane >> 4) * 4 + r;
            int f = (((t >> 2) & 3) << 1) | (t & 1);
#pragma unroll
            for (int nj = 0; nj < 4; nj++) {
                int s = nj * 16 + (lane & 15);
                int idx = t * 64 + (((s >> 3) ^ f) * 8) + (s & 7);
                Ph[wave][idx] = phv[nj][r];
                Pl[wave][idx] = plv[nj][r];
            }
        }
        // ---- PV (split 3-term) from buf[cur] ----
        bf16x8 pah[2], pal[2];
        {
            int t = lane & 15;
            int f = (((t >> 2) & 3) << 1) | (t & 1);
#pragma unroll
            for (int kk = 0; kk < 2; kk++) {
                int ch = (kk * 4 + (lane >> 4)) ^ f;
                pah[kk] = *(const bf16x8*)&Ph[wave][t * 64 + ch * 8];
                pal[kk] = *(const bf16x8*)&Pl[wave][t * 64 + ch * 8];
            }
        }
#pragma unroll
        for (int dj = 0; dj < 4; dj++) {
            int row = dj * 16 + (lane & 15);
#pragma unroll
            for (int kk = 0; kk < 2; kk++) {
                int ch = (kk * 4 + (lane >> 4)) ^ (row & 7);
                bf16x8 vfh = *(const bf16x8*)&Vsh[cur][row * 64 + ch * 8];
                bf16x8 vfl = *(const bf16x8*)&Vsl[cur][row * 64 + ch * 8];
                oacc[dj] = __builtin_amdgcn_mfma_f32_16x16x32_bf16(pah[kk], vfh, oacc[dj], 0, 0, 0);
                oacc[dj] = __builtin_amdgcn_mfma_f32_16x16x32_bf16(pal[kk], vfh, oacc[dj], 0, 0, 0);
                oacc[dj] = __builtin_amdgcn_mfma_f32_16x16x32_bf16(pah[kk], vfl, oacc[dj], 0, 0, 0);
            }
        }

        // ---- drain next-tile stage + bias prefetch; swap ----
        asm volatile("s_waitcnt vmcnt(0)" ::: "memory");
        __syncthreads();
    }

    // ---- epilogue: O = acc / l, split-store to obuf ----
#pragma unroll
    for (int r = 0; r < 4; r++) {
        float inv = 1.f / lrow[r];
        int t = t0 + wave * 16 + (lane >> 4) * 4 + r;
#pragma unroll
        for (int dj = 0; dj < 4; dj++) {
            float v = oacc[dj][r] * inv;
            unsigned short hh, ll;
            split_bf(v, hh, ll);
            size_t g = (size_t)(b * T_ + t) * E_ + h * 64 + dj * 16 + (lane & 15);
            oh[g] = hh;
            ol[g] = ll;
        }
    }
}

// ---------------------------------------------------------------------------
extern "C" void kernel_launch(void* const* d_in, const int* in_sizes, int n_in,
                              void* d_out, int out_size, void* d_ws,
                              size_t ws_size, hipStream_t stream) {
    const float* query = (const float*)d_in[0];
    const float* key   = (const float*)d_in[1];
    const float* value = (const float*)d_in[2];
    const void*  kpm   = d_in[3];
    const float* attn_bias = (const float*)d_in[4];
    const float* Wq = (const float*)d_in[5];
    const float* bq = (const float*)d_in[6];
    const float* Wk = (const float*)d_in[7];
    const float* bk = (const float*)d_in[8];
    const float* Wv = (const float*)d_in[9];
    const float* bv = (const float*)d_in[10];
    const float* Wo = (const float*)d_in[11];
    const float* bo = (const float*)d_in[12];
    float* out = (float*)d_out;

    char* ws = (char*)d_ws;
    const size_t MB = 1024 * 1024;
    // weight planes (2MB each)
    unsigned short* Wqh = (unsigned short*)(ws + 0 * MB);
    unsigned short* Wql = (unsigned short*)(ws + 2 * MB);
    unsigned short* Wkh = (unsigned short*)(ws + 4 * MB);
    unsigned short* Wkl = (unsigned short*)(ws + 6 * MB);
    unsigned short* Wvh = (unsigned short*)(ws + 8 * MB);
    unsigned short* Wvl = (unsigned short*)(ws + 10 * MB);
    unsigned short* Woh = (unsigned short*)(ws + 12 * MB);
    unsigned short* Wol = (unsigned short*)(ws + 14 * MB);
    // projection outputs (4MB each)
    unsigned short* qh = (unsigned short*)(ws + 16 * MB);
    unsigned short* ql = (unsigned short*)(ws + 20 * MB);
    unsigned short* kh = (unsigned short*)(ws + 24 * MB);
    unsigned short* kl = (unsigned short*)(ws + 28 * MB);
    unsigned short* vth = (unsigned short*)(ws + 32 * MB);  // V^T [E][B*S]
    unsigned short* vtl = (unsigned short*)(ws + 36 * MB);
    // activation planes (4MB each; dead after proj)
    unsigned short* xqh = (unsigned short*)(ws + 40 * MB);
    unsigned short* xql = (unsigned short*)(ws + 44 * MB);
    unsigned short* xkh = (unsigned short*)(ws + 48 * MB);
    unsigned short* xkl = (unsigned short*)(ws + 52 * MB);
    unsigned short* xvh = (unsigned short*)(ws + 56 * MB);
    unsigned short* xvl = (unsigned short*)(ws + 60 * MB);
    // flash output overlays activation planes (dead after proj)
    unsigned short* oh = (unsigned short*)(ws + 40 * MB);
    unsigned short* ol = (unsigned short*)(ws + 44 * MB);
    int* masknorm = (int*)(ws + 64 * MB);
    int* mode = masknorm + 2048;

    conv_split7_kernel<<<5120, 256, 0, stream>>>(
        Wq, Wk, Wv, Wo, query, key, value,
        Wqh, Wql, Wkh, Wkl, Wvh, Wvl, Woh, Wol,
        xqh, xql, xkh, xkl, xvh, xvl);
    mask_detect_kernel<<<1, 256, 0, stream>>>((const unsigned int*)kpm, mode);
    mask_norm_kernel<<<8, 256, 0, stream>>>(kpm, mode, masknorm);

    // q/k/v projections fused (SCALING folded into q); v computed transposed.
    proj_fused_kernel<<<768, 512, 0, stream>>>(
        xqh, xql, xkh, xkl, xvh, xvl,
        Wqh, Wql, Wkh, Wkl, Wvh, Wvl, bq, bk, bv,
        qh, ql, kh, kl, vth, vtl);

    // fused attention -> obuf hi/lo
    flash_kernel<<<512, 256, 0, stream>>>(qh, ql, kh, kl, vth, vtl, attn_bias,
                                          masknorm, oh, ol);

    // out = obuf . Wo^T + bo (fp32)
    gemm_out_kernel<<<512, 256, 0, stream>>>(oh, ol, Woh, Wol, bo, out);
}